// Round 3
// baseline (943.048 us; speedup 1.0000x reference)
//
#include <hip/hip_runtime.h>

#define B_    2
#define L_    2048
#define D_    768
#define H_    12
#define BL    4096      // B_*L_
#define CHUNK 128
#define NC    16        // L_/CHUNK
#define GOFF  3145728   // element offset of gate output within d_out
#define PI_F  3.14159265358979f

__device__ __forceinline__ float bf2f(unsigned short u) {
    return __uint_as_float(((unsigned int)u) << 16);
}
__device__ __forceinline__ unsigned short f2bf(float f) {
    unsigned int u = __float_as_uint(f);
    unsigned int r = (u + 0x7fffu + ((u >> 16) & 1u)) >> 16;
    return (unsigned short)r;
}
__device__ __forceinline__ float softplusf(float x) {
    return x > 20.f ? x : log1pf(expf(x));
}

// ---------------- dtype detector: fp32 low-half ushorts have garbage exponents ----
__global__ __launch_bounds__(256) void detect_kernel(const unsigned short* __restrict__ x,
                                                     int* __restrict__ flag)
{
    __shared__ int cnt;
    if (threadIdx.x == 0) cnt = 0;
    __syncthreads();
    int c = 0;
    #pragma unroll
    for (int i = 0; i < 16; i++) {
        unsigned short u = x[threadIdx.x * 16 + i];
        int e = (u >> 7) & 0xff;
        if (e < 100 || e > 140) c++;   // |v| outside [2^-27, 2^13] -> implausible for N(0,1) bf16
    }
    atomicAdd(&cnt, c);
    __syncthreads();
    if (threadIdx.x == 0) flag[0] = (cnt > 512) ? 1 : 0;   // 1 = inputs are fp32
}

// ---------------- canonicalize any input to bf16 ----------------
__global__ __launch_bounds__(256) void convert_kernel(const void* __restrict__ src,
                                                      unsigned short* __restrict__ dst,
                                                      int n, const int* __restrict__ flag)
{
    int i = blockIdx.x * 256 + threadIdx.x;
    if (i >= n) return;
    dst[i] = flag[0] ? f2bf(((const float*)src)[i]) : ((const unsigned short*)src)[i];
}

// ---------------- LayerNorm: one block per row ----------------
__global__ __launch_bounds__(256) void ln_kernel(
    const unsigned short* __restrict__ x,
    const unsigned short* __restrict__ gamma,
    const unsigned short* __restrict__ beta,
    unsigned short* __restrict__ xn)
{
    int row = blockIdx.x, t = threadIdx.x;
    const unsigned short* xr = x + (size_t)row * D_;
    float v[3];
    #pragma unroll
    for (int j = 0; j < 3; j++) v[j] = bf2f(xr[t + j * 256]);
    __shared__ float red[8];
    float s = v[0] + v[1] + v[2];
    #pragma unroll
    for (int m = 32; m >= 1; m >>= 1) s += __shfl_xor(s, m, 64);
    int wid = t >> 6;
    if ((t & 63) == 0) red[wid] = s;
    __syncthreads();
    float mean = (red[0] + red[1] + red[2] + red[3]) * (1.f / 768.f);
    float s2 = 0.f;
    #pragma unroll
    for (int j = 0; j < 3; j++) { float d = v[j] - mean; s2 += d * d; }
    #pragma unroll
    for (int m = 32; m >= 1; m >>= 1) s2 += __shfl_xor(s2, m, 64);
    if ((t & 63) == 0) red[4 + wid] = s2;
    __syncthreads();
    float var = (red[4] + red[5] + red[6] + red[7]) * (1.f / 768.f);
    float rs = rsqrtf(var + 1e-5f);
    #pragma unroll
    for (int j = 0; j < 3; j++) {
        int c = t + j * 256;
        float o = (v[j] - mean) * rs * bf2f(gamma[c]) + bf2f(beta[c]);
        xn[(size_t)row * D_ + c] = f2bf(o);
    }
}

// ---------------- Generic tiled GEMM, bf16 in/out, fp32 acc. ACT: 0 none, 1 silu ---
template<int ACT>
__global__ __launch_bounds__(256) void gemm_plain_kernel(
    const unsigned short* __restrict__ A,
    const unsigned short* __restrict__ Bm,
    const unsigned short* __restrict__ bias,
    unsigned short* __restrict__ Co,
    int M, int N, int K)
{
    __shared__ __align__(16) float As[16][64];
    __shared__ __align__(16) float Bs[16][64];
    int t = threadIdx.x;
    int tx = t & 15, ty = t >> 4;
    int m0 = blockIdx.y * 64, n0 = blockIdx.x * 64;
    int ar = t >> 2, ac4 = (t & 3) * 4;
    int br = t >> 4, bc4 = (t & 15) * 4;
    float acc[4][4] = {};
    for (int k0 = 0; k0 < K; k0 += 16) {
        ushort4 av = *(const ushort4*)&A[(size_t)(m0 + ar) * K + k0 + ac4];
        ushort4 bv = *(const ushort4*)&Bm[(size_t)(k0 + br) * N + n0 + bc4];
        __syncthreads();
        As[ac4 + 0][ar] = bf2f(av.x); As[ac4 + 1][ar] = bf2f(av.y);
        As[ac4 + 2][ar] = bf2f(av.z); As[ac4 + 3][ar] = bf2f(av.w);
        Bs[br][bc4 + 0] = bf2f(bv.x); Bs[br][bc4 + 1] = bf2f(bv.y);
        Bs[br][bc4 + 2] = bf2f(bv.z); Bs[br][bc4 + 3] = bf2f(bv.w);
        __syncthreads();
        #pragma unroll
        for (int kk = 0; kk < 16; kk++) {
            float4 a = *(const float4*)&As[kk][ty * 4];
            float4 b = *(const float4*)&Bs[kk][tx * 4];
            acc[0][0] += a.x * b.x; acc[0][1] += a.x * b.y; acc[0][2] += a.x * b.z; acc[0][3] += a.x * b.w;
            acc[1][0] += a.y * b.x; acc[1][1] += a.y * b.y; acc[1][2] += a.y * b.z; acc[1][3] += a.y * b.w;
            acc[2][0] += a.z * b.x; acc[2][1] += a.z * b.y; acc[2][2] += a.z * b.z; acc[2][3] += a.z * b.w;
            acc[3][0] += a.w * b.x; acc[3][1] += a.w * b.y; acc[3][2] += a.w * b.z; acc[3][3] += a.w * b.w;
        }
    }
    float bvals[4] = {0.f, 0.f, 0.f, 0.f};
    if (bias) {
        #pragma unroll
        for (int j = 0; j < 4; j++) bvals[j] = bf2f(bias[n0 + tx * 4 + j]);
    }
    #pragma unroll
    for (int i = 0; i < 4; i++) {
        int row = m0 + ty * 4 + i;
        ushort4 o; float vv[4];
        #pragma unroll
        for (int j = 0; j < 4; j++) {
            float v = acc[i][j] + bvals[j];
            if (ACT == 1) v = v / (1.f + expf(-v));
            vv[j] = v;
        }
        o.x = f2bf(vv[0]); o.y = f2bf(vv[1]); o.z = f2bf(vv[2]); o.w = f2bf(vv[3]);
        *(ushort4*)&Co[(size_t)row * N + n0 + tx * 4] = o;
    }
}

// ---------------- Fused up-projection + interference gate ----------------
// gate[row,c] = sigmoid( softplus(ts.Wsu[:,c]) * softplus(tc.Wcu[:,c]) *
//               cos(pi*tanh(ts.Wsu[:,768+c]) - pi*tanh(tc.Wcu[:,768+c])) * temp )
__global__ __launch_bounds__(256) void gate_fused_kernel(
    const unsigned short* __restrict__ tsem,
    const unsigned short* __restrict__ tctx,
    const unsigned short* __restrict__ Wsu,
    const unsigned short* __restrict__ Wcu,
    const unsigned short* __restrict__ tempc,
    void* __restrict__ dout, const int* __restrict__ flag)
{
    __shared__ __align__(16) float As1[16][64], As2[16][64];
    __shared__ __align__(16) float Ba1[16][64], Bp1[16][64], Ba2[16][64], Bp2[16][64];
    int t = threadIdx.x;
    int tx = t & 15, ty = t >> 4;
    int m0 = blockIdx.y * 64, c0 = blockIdx.x * 64;
    int ar = t >> 2, ac4 = (t & 3) * 4;
    int br = t >> 4, bc4 = (t & 15) * 4;
    float asa[4][4] = {}, asp[4][4] = {}, aca[4][4] = {}, acp[4][4] = {};
    for (int k0 = 0; k0 < 128; k0 += 16) {
        ushort4 a1 = *(const ushort4*)&tsem[(size_t)(m0 + ar) * 128 + k0 + ac4];
        ushort4 a2 = *(const ushort4*)&tctx[(size_t)(m0 + ar) * 128 + k0 + ac4];
        ushort4 b1 = *(const ushort4*)&Wsu[(size_t)(k0 + br) * 1536 + c0 + bc4];
        ushort4 b2 = *(const ushort4*)&Wsu[(size_t)(k0 + br) * 1536 + 768 + c0 + bc4];
        ushort4 b3 = *(const ushort4*)&Wcu[(size_t)(k0 + br) * 1536 + c0 + bc4];
        ushort4 b4 = *(const ushort4*)&Wcu[(size_t)(k0 + br) * 1536 + 768 + c0 + bc4];
        __syncthreads();
        As1[ac4 + 0][ar] = bf2f(a1.x); As1[ac4 + 1][ar] = bf2f(a1.y);
        As1[ac4 + 2][ar] = bf2f(a1.z); As1[ac4 + 3][ar] = bf2f(a1.w);
        As2[ac4 + 0][ar] = bf2f(a2.x); As2[ac4 + 1][ar] = bf2f(a2.y);
        As2[ac4 + 2][ar] = bf2f(a2.z); As2[ac4 + 3][ar] = bf2f(a2.w);
        Ba1[br][bc4 + 0] = bf2f(b1.x); Ba1[br][bc4 + 1] = bf2f(b1.y);
        Ba1[br][bc4 + 2] = bf2f(b1.z); Ba1[br][bc4 + 3] = bf2f(b1.w);
        Bp1[br][bc4 + 0] = bf2f(b2.x); Bp1[br][bc4 + 1] = bf2f(b2.y);
        Bp1[br][bc4 + 2] = bf2f(b2.z); Bp1[br][bc4 + 3] = bf2f(b2.w);
        Ba2[br][bc4 + 0] = bf2f(b3.x); Ba2[br][bc4 + 1] = bf2f(b3.y);
        Ba2[br][bc4 + 2] = bf2f(b3.z); Ba2[br][bc4 + 3] = bf2f(b3.w);
        Bp2[br][bc4 + 0] = bf2f(b4.x); Bp2[br][bc4 + 1] = bf2f(b4.y);
        Bp2[br][bc4 + 2] = bf2f(b4.z); Bp2[br][bc4 + 3] = bf2f(b4.w);
        __syncthreads();
        #pragma unroll
        for (int kk = 0; kk < 16; kk++) {
            float4 va1 = *(const float4*)&As1[kk][ty * 4];
            float4 va2 = *(const float4*)&As2[kk][ty * 4];
            float4 wa1 = *(const float4*)&Ba1[kk][tx * 4];
            float4 wp1 = *(const float4*)&Bp1[kk][tx * 4];
            float4 wa2 = *(const float4*)&Ba2[kk][tx * 4];
            float4 wp2 = *(const float4*)&Bp2[kk][tx * 4];
            float a1v[4] = {va1.x, va1.y, va1.z, va1.w};
            float a2v[4] = {va2.x, va2.y, va2.z, va2.w};
            float w1a[4] = {wa1.x, wa1.y, wa1.z, wa1.w};
            float w1p[4] = {wp1.x, wp1.y, wp1.z, wp1.w};
            float w2a[4] = {wa2.x, wa2.y, wa2.z, wa2.w};
            float w2p[4] = {wp2.x, wp2.y, wp2.z, wp2.w};
            #pragma unroll
            for (int i = 0; i < 4; i++) {
                #pragma unroll
                for (int j = 0; j < 4; j++) {
                    asa[i][j] += a1v[i] * w1a[j];
                    asp[i][j] += a1v[i] * w1p[j];
                    aca[i][j] += a2v[i] * w2a[j];
                    acp[i][j] += a2v[i] * w2p[j];
                }
            }
        }
    }
    float tempv = bf2f(tempc[0]);
    int fl = flag[0];
    #pragma unroll
    for (int i = 0; i < 4; i++) {
        int row = m0 + ty * 4 + i;
        float gv[4];
        #pragma unroll
        for (int j = 0; j < 4; j++) {
            float sa = softplusf(asa[i][j]);
            float sp = tanhf(asp[i][j]) * PI_F;
            float ca = softplusf(aca[i][j]);
            float cp = tanhf(acp[i][j]) * PI_F;
            float inter = sa * ca * cosf(sp - cp) * tempv;
            gv[j] = 1.f / (1.f + expf(-inter));
        }
        size_t off = (size_t)GOFF + (size_t)row * D_ + c0 + tx * 4;
        if (fl) {
            float4 o = make_float4(gv[0], gv[1], gv[2], gv[3]);
            *(float4*)&((float*)dout)[off] = o;
        } else {
            ushort4 o;
            o.x = f2bf(gv[0]); o.y = f2bf(gv[1]); o.z = f2bf(gv[2]); o.w = f2bf(gv[3]);
            *(ushort4*)&((unsigned short*)dout)[off] = o;
        }
    }
}

// ---------------- qkv GEMM for 3-head group g, fused elu/gate epilogue ------------
// Output qkvg: (BL, 576) = [q_f 192 | k_f 192 | v 192] for heads 3g..3g+2
__global__ __launch_bounds__(256) void gemm_qkvg_kernel(
    const unsigned short* __restrict__ A,      // xn (BL,768)
    const unsigned short* __restrict__ Bm,     // W_qkv (768,2304)
    const unsigned short* __restrict__ bias,   // (2304)
    const void* __restrict__ dout,             // gate at GOFF
    const int* __restrict__ flag,
    int g,
    unsigned short* __restrict__ Co)
{
    __shared__ __align__(16) float As[16][64];
    __shared__ __align__(16) float Bs[16][64];
    int t = threadIdx.x;
    int tx = t & 15, ty = t >> 4;
    int bx = blockIdx.x;               // 0..8
    int seg = bx / 3, lx = bx - seg * 3;
    int bcol0 = seg * 768 + g * 192 + lx * 64;
    int m0 = blockIdx.y * 64;
    int ar = t >> 2, ac4 = (t & 3) * 4;
    int br = t >> 4, bc4 = (t & 15) * 4;
    float acc[4][4] = {};
    for (int k0 = 0; k0 < 768; k0 += 16) {
        ushort4 av = *(const ushort4*)&A[(size_t)(m0 + ar) * 768 + k0 + ac4];
        ushort4 bv = *(const ushort4*)&Bm[(size_t)(k0 + br) * 2304 + bcol0 + bc4];
        __syncthreads();
        As[ac4 + 0][ar] = bf2f(av.x); As[ac4 + 1][ar] = bf2f(av.y);
        As[ac4 + 2][ar] = bf2f(av.z); As[ac4 + 3][ar] = bf2f(av.w);
        Bs[br][bc4 + 0] = bf2f(bv.x); Bs[br][bc4 + 1] = bf2f(bv.y);
        Bs[br][bc4 + 2] = bf2f(bv.z); Bs[br][bc4 + 3] = bf2f(bv.w);
        __syncthreads();
        #pragma unroll
        for (int kk = 0; kk < 16; kk++) {
            float4 a = *(const float4*)&As[kk][ty * 4];
            float4 b = *(const float4*)&Bs[kk][tx * 4];
            acc[0][0] += a.x * b.x; acc[0][1] += a.x * b.y; acc[0][2] += a.x * b.z; acc[0][3] += a.x * b.w;
            acc[1][0] += a.y * b.x; acc[1][1] += a.y * b.y; acc[1][2] += a.y * b.z; acc[1][3] += a.y * b.w;
            acc[2][0] += a.z * b.x; acc[2][1] += a.z * b.y; acc[2][2] += a.z * b.z; acc[2][3] += a.z * b.w;
            acc[3][0] += a.w * b.x; acc[3][1] += a.w * b.y; acc[3][2] += a.w * b.z; acc[3][3] += a.w * b.w;
        }
    }
    int fl = flag[0];
    float bvals[4];
    #pragma unroll
    for (int j = 0; j < 4; j++) bvals[j] = bf2f(bias[bcol0 + tx * 4 + j]);
    #pragma unroll
    for (int i = 0; i < 4; i++) {
        int row = m0 + ty * 4 + i;
        ushort4 o; float vv[4];
        #pragma unroll
        for (int j = 0; j < 4; j++) {
            float v = acc[i][j] + bvals[j];
            if (seg == 0) {                       // q: elu+1
                v = v > 0.f ? v + 1.f : expf(v);
            } else if (seg == 1) {                // k: gate, then elu+1
                int cD = g * 192 + lx * 64 + tx * 4 + j;
                size_t goffe = (size_t)GOFF + (size_t)row * D_ + cD;
                float gg = fl ? ((const float*)dout)[goffe]
                              : bf2f(((const unsigned short*)dout)[goffe]);
                v *= (1.f + gg);
                v = v > 0.f ? v + 1.f : expf(v);
            }                                     // v: passthrough
            vv[j] = v;
        }
        o.x = f2bf(vv[0]); o.y = f2bf(vv[1]); o.z = f2bf(vv[2]); o.w = f2bf(vv[3]);
        *(ushort4*)&Co[(size_t)row * 576 + bx * 64 + tx * 4] = o;
    }
}

// ---------------- Pass A: per-chunk sums of k (x) v and k (group of 3 heads) ------
__global__ __launch_bounds__(256) void chunk_sum_kernel(
    const unsigned short* __restrict__ qkvg,
    float* __restrict__ Msum, float* __restrict__ Zsum)
{
    int blk = blockIdx.x;                 // 0..95
    int bhl = blk / NC, cc = blk - bhl * NC;
    int b = bhl / 3, hl = bhl - b * 3;
    int t = threadIdx.x, e = t & 63, g = t >> 6;
    int r = t >> 4, c4 = (t & 15) * 4;
    __shared__ __align__(16) float kb[1024], vb[1024];
    float S[16] = {}; float z[16] = {};
    size_t rowbase = (size_t)(b * L_ + cc * CHUNK);
    const unsigned short* kg = qkvg + rowbase * 576 + 192 + hl * 64;
    const unsigned short* vg = qkvg + rowbase * 576 + 384 + hl * 64;
    for (int t0 = 0; t0 < CHUNK; t0 += 16) {
        ushort4 kk4 = *(const ushort4*)&kg[(size_t)(t0 + r) * 576 + c4];
        ushort4 vv4 = *(const ushort4*)&vg[(size_t)(t0 + r) * 576 + c4];
        __syncthreads();
        kb[r * 64 + c4 + 0] = bf2f(kk4.x); kb[r * 64 + c4 + 1] = bf2f(kk4.y);
        kb[r * 64 + c4 + 2] = bf2f(kk4.z); kb[r * 64 + c4 + 3] = bf2f(kk4.w);
        vb[r * 64 + c4 + 0] = bf2f(vv4.x); vb[r * 64 + c4 + 1] = bf2f(vv4.y);
        vb[r * 64 + c4 + 2] = bf2f(vv4.z); vb[r * 64 + c4 + 3] = bf2f(vv4.w);
        __syncthreads();
        for (int lr = 0; lr < 16; lr++) {
            float ve = vb[lr * 64 + e];
            #pragma unroll
            for (int i4 = 0; i4 < 4; i4++) {
                float4 kf = *(const float4*)&kb[lr * 64 + g * 16 + i4 * 4];
                int i = i4 * 4;
                S[i + 0] += kf.x * ve; z[i + 0] += kf.x;
                S[i + 1] += kf.y * ve; z[i + 1] += kf.y;
                S[i + 2] += kf.z * ve; z[i + 2] += kf.z;
                S[i + 3] += kf.w * ve; z[i + 3] += kf.w;
            }
        }
    }
    float* mo = Msum + (size_t)blk * 4096;
    #pragma unroll
    for (int i = 0; i < 16; i++) mo[(g * 16 + i) * 64 + e] = S[i];
    if (e == 0) {
        float* zo = Zsum + (size_t)blk * 64;
        #pragma unroll
        for (int i = 0; i < 16; i++) zo[g * 16 + i] = z[i];
    }
}

// ---------------- Pass B: exclusive prefix over chunks (grid = 6) -----------------
__global__ __launch_bounds__(256) void prefix_kernel(
    float* __restrict__ Msum, float* __restrict__ Zsum)
{
    int bh = blockIdx.x, t = threadIdx.x;
    float run[16];
    #pragma unroll
    for (int j = 0; j < 16; j++) run[j] = 0.f;
    for (int c = 0; c < NC; c++) {
        float* p = Msum + ((size_t)bh * NC + c) * 4096 + t * 16;
        #pragma unroll
        for (int j = 0; j < 16; j += 4) {
            float4 v = *(float4*)&p[j];
            float4 o = make_float4(run[j], run[j + 1], run[j + 2], run[j + 3]);
            run[j] += v.x; run[j + 1] += v.y; run[j + 2] += v.z; run[j + 3] += v.w;
            *(float4*)&p[j] = o;
        }
    }
    if (t < 64) {
        float rz = 0.f;
        for (int c = 0; c < NC; c++) {
            float* pz = Zsum + ((size_t)bh * NC + c) * 64 + t;
            float v = *pz; *pz = rz; rz += v;
        }
    }
}

// ---------------- Pass C: within-chunk causal scan seeded by prefix ---------------
__global__ __launch_bounds__(256) void chunk_scan_kernel(
    const unsigned short* __restrict__ qkvg,
    const float* __restrict__ Msum, const float* __restrict__ Zsum,
    unsigned short* __restrict__ attnb, int grp)
{
    int blk = blockIdx.x;
    int bhl = blk / NC, cc = blk - bhl * NC;
    int b = bhl / 3, hl = bhl - b * 3;
    int t = threadIdx.x, e = t & 63, g = t >> 6;
    int r = t >> 4, c4 = (t & 15) * 4;
    __shared__ __align__(16) float qb[1024], kb[1024], vb[1024];
    __shared__ float numred[256];
    __shared__ float denred[4];
    float S[16], z[16];
    const float* mp = Msum + (size_t)blk * 4096;
    const float* zp = Zsum + (size_t)blk * 64;
    #pragma unroll
    for (int i = 0; i < 16; i++) { S[i] = mp[(g * 16 + i) * 64 + e]; z[i] = zp[g * 16 + i]; }
    size_t rowbase = (size_t)(b * L_ + cc * CHUNK);
    const unsigned short* qg = qkvg + rowbase * 576 + hl * 64;
    const unsigned short* kg = qkvg + rowbase * 576 + 192 + hl * 64;
    const unsigned short* vg = qkvg + rowbase * 576 + 384 + hl * 64;
    unsigned short* abase = attnb + rowbase * D_ + (grp * 3 + hl) * 64;
    for (int t0 = 0; t0 < CHUNK; t0 += 16) {
        ushort4 qq4 = *(const ushort4*)&qg[(size_t)(t0 + r) * 576 + c4];
        ushort4 kk4 = *(const ushort4*)&kg[(size_t)(t0 + r) * 576 + c4];
        ushort4 vv4 = *(const ushort4*)&vg[(size_t)(t0 + r) * 576 + c4];
        qb[r * 64 + c4 + 0] = bf2f(qq4.x); qb[r * 64 + c4 + 1] = bf2f(qq4.y);
        qb[r * 64 + c4 + 2] = bf2f(qq4.z); qb[r * 64 + c4 + 3] = bf2f(qq4.w);
        kb[r * 64 + c4 + 0] = bf2f(kk4.x); kb[r * 64 + c4 + 1] = bf2f(kk4.y);
        kb[r * 64 + c4 + 2] = bf2f(kk4.z); kb[r * 64 + c4 + 3] = bf2f(kk4.w);
        vb[r * 64 + c4 + 0] = bf2f(vv4.x); vb[r * 64 + c4 + 1] = bf2f(vv4.y);
        vb[r * 64 + c4 + 2] = bf2f(vv4.z); vb[r * 64 + c4 + 3] = bf2f(vv4.w);
        __syncthreads();
        for (int lr = 0; lr < 16; lr++) {
            float ve = vb[lr * 64 + e];
            float num = 0.f, den = 0.f;
            #pragma unroll
            for (int i4 = 0; i4 < 4; i4++) {
                float4 kf = *(const float4*)&kb[lr * 64 + g * 16 + i4 * 4];
                float4 qf = *(const float4*)&qb[lr * 64 + g * 16 + i4 * 4];
                int i = i4 * 4;
                S[i + 0] += kf.x * ve; num += qf.x * S[i + 0]; z[i + 0] += kf.x; den += qf.x * z[i + 0];
                S[i + 1] += kf.y * ve; num += qf.y * S[i + 1]; z[i + 1] += kf.y; den += qf.y * z[i + 1];
                S[i + 2] += kf.z * ve; num += qf.z * S[i + 2]; z[i + 2] += kf.z; den += qf.z * z[i + 2];
                S[i + 3] += kf.w * ve; num += qf.w * S[i + 3]; z[i + 3] += kf.w; den += qf.w * z[i + 3];
            }
            numred[t] = num;
            if (e == 0) denred[g] = den;
            __syncthreads();
            if (g == 0) {
                float nn = numred[e] + numred[64 + e] + numred[128 + e] + numred[192 + e];
                float dd = denred[0] + denred[1] + denred[2] + denred[3] + 1e-6f;
                abase[(size_t)(t0 + lr) * D_ + e] = f2bf(nn / dd);
            }
            __syncthreads();
        }
    }
}

// ---------------- Output projection with dtype-flagged store ----------------------
__global__ __launch_bounds__(256) void gemm_proj_kernel(
    const unsigned short* __restrict__ A,      // attnb (BL,768)
    const unsigned short* __restrict__ Bm,     // W_proj (768,768)
    const unsigned short* __restrict__ bias,   // (768)
    void* __restrict__ dout, const int* __restrict__ flag)
{
    __shared__ __align__(16) float As[16][64];
    __shared__ __align__(16) float Bs[16][64];
    int t = threadIdx.x;
    int tx = t & 15, ty = t >> 4;
    int m0 = blockIdx.y * 64, n0 = blockIdx.x * 64;
    int ar = t >> 2, ac4 = (t & 3) * 4;
    int br = t >> 4, bc4 = (t & 15) * 4;
    float acc[4][4] = {};
    for (int k0 = 0; k0 < 768; k0 += 16) {
        ushort4 av = *(const ushort4*)&A[(size_t)(m0 + ar) * 768 + k0 + ac4];
        ushort4 bv = *(const ushort4*)&Bm[(size_t)(k0 + br) * 768 + n0 + bc4];
        __syncthreads();
        As[ac4 + 0][ar] = bf2f(av.x); As[ac4 + 1][ar] = bf2f(av.y);
        As[ac4 + 2][ar] = bf2f(av.z); As[ac4 + 3][ar] = bf2f(av.w);
        Bs[br][bc4 + 0] = bf2f(bv.x); Bs[br][bc4 + 1] = bf2f(bv.y);
        Bs[br][bc4 + 2] = bf2f(bv.z); Bs[br][bc4 + 3] = bf2f(bv.w);
        __syncthreads();
        #pragma unroll
        for (int kk = 0; kk < 16; kk++) {
            float4 a = *(const float4*)&As[kk][ty * 4];
            float4 b = *(const float4*)&Bs[kk][tx * 4];
            acc[0][0] += a.x * b.x; acc[0][1] += a.x * b.y; acc[0][2] += a.x * b.z; acc[0][3] += a.x * b.w;
            acc[1][0] += a.y * b.x; acc[1][1] += a.y * b.y; acc[1][2] += a.y * b.z; acc[1][3] += a.y * b.w;
            acc[2][0] += a.z * b.x; acc[2][1] += a.z * b.y; acc[2][2] += a.z * b.z; acc[2][3] += a.z * b.w;
            acc[3][0] += a.w * b.x; acc[3][1] += a.w * b.y; acc[3][2] += a.w * b.z; acc[3][3] += a.w * b.w;
        }
    }
    int fl = flag[0];
    float bvals[4];
    #pragma unroll
    for (int j = 0; j < 4; j++) bvals[j] = bf2f(bias[n0 + tx * 4 + j]);
    #pragma unroll
    for (int i = 0; i < 4; i++) {
        int row = m0 + ty * 4 + i;
        size_t off = (size_t)row * D_ + n0 + tx * 4;
        float v0 = acc[i][0] + bvals[0], v1 = acc[i][1] + bvals[1];
        float v2 = acc[i][2] + bvals[2], v3 = acc[i][3] + bvals[3];
        if (fl) {
            *(float4*)&((float*)dout)[off] = make_float4(v0, v1, v2, v3);
        } else {
            ushort4 o;
            o.x = f2bf(v0); o.y = f2bf(v1); o.z = f2bf(v2); o.w = f2bf(v3);
            *(ushort4*)&((unsigned short*)dout)[off] = o;
        }
    }
}

extern "C" void kernel_launch(void* const* d_in, const int* in_sizes, int n_in,
                              void* d_out, int out_size, void* d_ws, size_t ws_size,
                              hipStream_t stream)
{
    // ---- workspace (~26.9 MB) ----
    char* w = (char*)d_ws;
    auto alloc = [&](size_t bytes) { void* p = (void*)w; w += (bytes + 255) & ~(size_t)255; return p; };
    int*            flagp   = (int*)alloc(256);
    unsigned short* x_c     = (unsigned short*)alloc((size_t)BL * D_ * 2);
    unsigned short* xn      = (unsigned short*)alloc((size_t)BL * D_ * 2);
    unsigned short* attnb   = (unsigned short*)alloc((size_t)BL * D_ * 2);
    unsigned short* Wqkv_c  = (unsigned short*)alloc((size_t)768 * 2304 * 2);
    unsigned short* bqkv_c  = (unsigned short*)alloc((size_t)2304 * 2);
    unsigned short* Wsd_c   = (unsigned short*)alloc((size_t)768 * 128 * 2);
    unsigned short* Wsu_c   = (unsigned short*)alloc((size_t)128 * 1536 * 2);
    unsigned short* Wcd_c   = (unsigned short*)alloc((size_t)768 * 128 * 2);
    unsigned short* Wcu_c   = (unsigned short*)alloc((size_t)128 * 1536 * 2);
    unsigned short* Wproj_c = (unsigned short*)alloc((size_t)768 * 768 * 2);
    unsigned short* bproj_c = (unsigned short*)alloc((size_t)768 * 2);
    unsigned short* gamma_c = (unsigned short*)alloc((size_t)768 * 2);
    unsigned short* beta_c  = (unsigned short*)alloc((size_t)768 * 2);
    unsigned short* temp_c  = (unsigned short*)alloc(256);
    unsigned short* tsem    = (unsigned short*)alloc((size_t)BL * 128 * 2);
    unsigned short* tctx    = (unsigned short*)alloc((size_t)BL * 128 * 2);
    float*          Zsum    = (float*)alloc((size_t)6 * NC * 64 * 4);
    // out0 region as scratch until the final projection (exact fit in bf16 mode):
    unsigned short* qkvg = (unsigned short*)d_out;                       // BL*576 bf16 = 4,718,592 B
    float*          Msum = (float*)((char*)d_out + (size_t)BL * 576 * 2); // 6*NC*4096 f32 = 1,572,864 B

    dim3 blk(256);
    // 0. dtype detect + canonicalize all inputs to bf16
    detect_kernel<<<1, blk, 0, stream>>>((const unsigned short*)d_in[0], flagp);
    unsigned short* dsts[12] = {x_c, Wqkv_c, bqkv_c, Wsd_c, Wsu_c, Wcd_c, Wcu_c,
                                temp_c, Wproj_c, bproj_c, gamma_c, beta_c};
    for (int i = 0; i < 12; i++) {
        int n = in_sizes[i];
        convert_kernel<<<(n + 255) / 256, blk, 0, stream>>>(d_in[i], dsts[i], n, flagp);
    }
    // 1. LayerNorm
    ln_kernel<<<BL, blk, 0, stream>>>(x_c, gamma_c, beta_c, xn);
    // 2. low-rank down-projections with silu
    gemm_plain_kernel<1><<<dim3(2, BL / 64), blk, 0, stream>>>(x_c, Wsd_c, nullptr, tsem, BL, 128, 768);
    gemm_plain_kernel<1><<<dim3(2, BL / 64), blk, 0, stream>>>(x_c, Wcd_c, nullptr, tctx, BL, 128, 768);
    // 3. fused up-projection + interference gate -> d_out gate region
    gate_fused_kernel<<<dim3(12, BL / 64), blk, 0, stream>>>(tsem, tctx, Wsu_c, Wcu_c, temp_c, d_out, flagp);
    // 4. per-group (3 heads) qkv GEMM + chunked causal linear attention
    for (int g = 0; g < 4; g++) {
        gemm_qkvg_kernel<<<dim3(9, BL / 64), blk, 0, stream>>>(xn, Wqkv_c, bqkv_c, d_out, flagp, g, qkvg);
        chunk_sum_kernel<<<6 * NC, blk, 0, stream>>>(qkvg, Msum, Zsum);
        prefix_kernel<<<6, blk, 0, stream>>>(Msum, Zsum);
        chunk_scan_kernel<<<6 * NC, blk, 0, stream>>>(qkvg, Msum, Zsum, attnb, g);
    }
    // 5. output projection (overwrites out0 scratch; dtype-flagged store)
    gemm_proj_kernel<<<dim3(12, BL / 64), blk, 0, stream>>>(attnb, Wproj_c, bproj_c, d_out, flagp);
}

// Round 4
// 406.004 us; speedup vs baseline: 2.3228x; 2.3228x over previous
//
#include <hip/hip_runtime.h>

#define B_    2
#define L_    2048
#define D_    768
#define H_    12
#define BL    4096      // B_*L_
#define BH    24        // B_*H_
#define CHUNK 128
#define NC    16        // L_/CHUNK
#define GOFF  3145728   // element offset of gate output within d_out
#define PI_F  3.14159265358979f
#define LDA   40        // LDS row stride (ushorts): 80 B, 16B-aligned, breaks pow2 banks

typedef __bf16 bf16x8 __attribute__((ext_vector_type(8)));
typedef float  f32x4  __attribute__((ext_vector_type(4)));
typedef unsigned short us8 __attribute__((ext_vector_type(8)));

__device__ __forceinline__ float bf2f(unsigned short u) {
    return __uint_as_float(((unsigned int)u) << 16);
}
__device__ __forceinline__ unsigned short f2bf(float f) {
    unsigned int u = __float_as_uint(f);
    unsigned int r = (u + 0x7fffu + ((u >> 16) & 1u)) >> 16;
    return (unsigned short)r;
}
__device__ __forceinline__ float softplusf(float x) {
    return x > 20.f ? x : log1pf(expf(x));
}

// ---------------- dtype detector: fp32 low-half ushorts have garbage exponents ----
__global__ __launch_bounds__(256) void detect_kernel(const unsigned short* __restrict__ x,
                                                     int* __restrict__ flag)
{
    __shared__ int cnt;
    if (threadIdx.x == 0) cnt = 0;
    __syncthreads();
    int c = 0;
    #pragma unroll
    for (int i = 0; i < 16; i++) {
        unsigned short u = x[threadIdx.x * 16 + i];
        int e = (u >> 7) & 0xff;
        if (e < 100 || e > 140) c++;
    }
    atomicAdd(&cnt, c);
    __syncthreads();
    if (threadIdx.x == 0) flag[0] = (cnt > 512) ? 1 : 0;   // 1 = inputs are fp32
}

// ---------------- canonicalize any input to bf16 ----------------
__global__ __launch_bounds__(256) void convert_kernel(const void* __restrict__ src,
                                                      unsigned short* __restrict__ dst,
                                                      int n, const int* __restrict__ flag)
{
    int i = blockIdx.x * 256 + threadIdx.x;
    if (i >= n) return;
    dst[i] = flag[0] ? f2bf(((const float*)src)[i]) : ((const unsigned short*)src)[i];
}

// ---------------- transpose + convert: src (K x N) -> dst (N x K) bf16 ------------
__global__ __launch_bounds__(256) void transpose_convert_kernel(
    const void* __restrict__ src, unsigned short* __restrict__ dst,
    int K, int N, const int* __restrict__ flag)
{
    __shared__ unsigned short tile[32][33];
    int bx = blockIdx.x * 32;   // n block
    int by = blockIdx.y * 32;   // k block
    int tx = threadIdx.x & 31, tyb = threadIdx.x >> 5;   // tyb: 0..7
    int fl = flag[0];
    #pragma unroll
    for (int i = 0; i < 4; i++) {
        int k = by + tyb * 4 + i, n = bx + tx;
        size_t off = (size_t)k * N + n;
        unsigned short v = fl ? f2bf(((const float*)src)[off]) : ((const unsigned short*)src)[off];
        tile[tyb * 4 + i][tx] = v;
    }
    __syncthreads();
    #pragma unroll
    for (int i = 0; i < 4; i++) {
        int n = bx + tyb * 4 + i, k = by + tx;
        dst[(size_t)n * K + k] = tile[tx][tyb * 4 + i];
    }
}

// ---------------- LayerNorm: one block per row ----------------
__global__ __launch_bounds__(256) void ln_kernel(
    const unsigned short* __restrict__ x,
    const unsigned short* __restrict__ gamma,
    const unsigned short* __restrict__ beta,
    unsigned short* __restrict__ xn)
{
    int row = blockIdx.x, t = threadIdx.x;
    const unsigned short* xr = x + (size_t)row * D_;
    float v[3];
    #pragma unroll
    for (int j = 0; j < 3; j++) v[j] = bf2f(xr[t + j * 256]);
    __shared__ float red[8];
    float s = v[0] + v[1] + v[2];
    #pragma unroll
    for (int m = 32; m >= 1; m >>= 1) s += __shfl_xor(s, m, 64);
    int wid = t >> 6;
    if ((t & 63) == 0) red[wid] = s;
    __syncthreads();
    float mean = (red[0] + red[1] + red[2] + red[3]) * (1.f / 768.f);
    float s2 = 0.f;
    #pragma unroll
    for (int j = 0; j < 3; j++) { float d = v[j] - mean; s2 += d * d; }
    #pragma unroll
    for (int m = 32; m >= 1; m >>= 1) s2 += __shfl_xor(s2, m, 64);
    if ((t & 63) == 0) red[4 + wid] = s2;
    __syncthreads();
    float var = (red[4] + red[5] + red[6] + red[7]) * (1.f / 768.f);
    float rs = rsqrtf(var + 1e-5f);
    #pragma unroll
    for (int j = 0; j < 3; j++) {
        int c = t + j * 256;
        float o = (v[j] - mean) * rs * bf2f(gamma[c]) + bf2f(beta[c]);
        xn[(size_t)row * D_ + c] = f2bf(o);
    }
}

// ---------------- MFMA GEMM: out = epi(A @ BT^T + bias) ---------------------------
// A: 4096 x K, row stride lda (bf16).  BT: N x K row-major (bf16, pre-transposed).
// 128x128 tile/block, 4 waves, each wave a 64x64 region as 4x4 mfma_16x16x32 tiles.
// EPI: 0 = bias-only, 1 = silu, 2 = qkv transform (elu+1 / gate+elu+1 / pass),
//      3 = flagged fp32-or-bf16 store (final projection)
template<int EPI>
__global__ __launch_bounds__(256) void mfma_gemm_kernel(
    const unsigned short* __restrict__ A, int lda,
    const unsigned short* __restrict__ BT,
    const unsigned short* __restrict__ bias,   // nullable
    const void* __restrict__ gate,             // EPI==2: d_out (gate at GOFF)
    void* __restrict__ outp,
    const int* __restrict__ flag,
    int N, int K)
{
    __shared__ unsigned short As[128 * LDA];
    __shared__ unsigned short Bs[128 * LDA];
    int t = threadIdx.x;
    int lane = t & 63, wave = t >> 6, quad = lane >> 4, l16 = lane & 15;
    int wm = (wave & 1) * 64, wn = (wave >> 1) * 64;
    int m0 = blockIdx.y * 128, n0 = blockIdx.x * 128;
    int sr = t >> 2, sc = (t & 3) * 8;
    f32x4 acc[4][4];
    #pragma unroll
    for (int i = 0; i < 4; i++)
        #pragma unroll
        for (int j = 0; j < 4; j++) acc[i][j] = (f32x4){0.f, 0.f, 0.f, 0.f};

    for (int k0 = 0; k0 < K; k0 += 32) {
        us8 a0 = *(const us8*)&A[(size_t)(m0 + sr) * lda + k0 + sc];
        us8 a1 = *(const us8*)&A[(size_t)(m0 + 64 + sr) * lda + k0 + sc];
        us8 b0 = *(const us8*)&BT[(size_t)(n0 + sr) * K + k0 + sc];
        us8 b1 = *(const us8*)&BT[(size_t)(n0 + 64 + sr) * K + k0 + sc];
        __syncthreads();
        *(us8*)&As[sr * LDA + sc] = a0;
        *(us8*)&As[(64 + sr) * LDA + sc] = a1;
        *(us8*)&Bs[sr * LDA + sc] = b0;
        *(us8*)&Bs[(64 + sr) * LDA + sc] = b1;
        __syncthreads();
        bf16x8 af[4], bfr[4];
        #pragma unroll
        for (int i = 0; i < 4; i++)
            af[i] = *(const bf16x8*)&As[(wm + i * 16 + l16) * LDA + quad * 8];
        #pragma unroll
        for (int j = 0; j < 4; j++)
            bfr[j] = *(const bf16x8*)&Bs[(wn + j * 16 + l16) * LDA + quad * 8];
        #pragma unroll
        for (int i = 0; i < 4; i++)
            #pragma unroll
            for (int j = 0; j < 4; j++)
                acc[i][j] = __builtin_amdgcn_mfma_f32_16x16x32_bf16(af[i], bfr[j], acc[i][j], 0, 0, 0);
    }

    int fl = (EPI >= 2) ? flag[0] : 0;
    #pragma unroll
    for (int j = 0; j < 4; j++) {
        int col = n0 + wn + j * 16 + l16;
        float bv = bias ? bf2f(bias[col]) : 0.f;
        #pragma unroll
        for (int i = 0; i < 4; i++) {
            #pragma unroll
            for (int r = 0; r < 4; r++) {
                int row = m0 + wm + i * 16 + quad * 4 + r;
                float v = acc[i][j][r] + bv;
                if (EPI == 1) v = v / (1.f + expf(-v));            // silu
                if (EPI == 2) {
                    if (col < D_) {                                 // q: elu+1
                        v = v > 0.f ? v + 1.f : expf(v);
                    } else if (col < 2 * D_) {                      // k: gate, elu+1
                        size_t go = (size_t)GOFF + (size_t)row * D_ + (col - D_);
                        float gg = fl ? ((const float*)gate)[go]
                                      : bf2f(((const unsigned short*)gate)[go]);
                        v *= (1.f + gg);
                        v = v > 0.f ? v + 1.f : expf(v);
                    }                                               // v: pass
                }
                size_t off = (size_t)row * N + col;
                if (EPI == 3) {
                    if (fl) ((float*)outp)[off] = v;
                    else    ((unsigned short*)outp)[off] = f2bf(v);
                } else {
                    ((unsigned short*)outp)[off] = f2bf(v);
                }
            }
        }
    }
}

// ---------------- Gate: elementwise sinusoidal interference ----------------
__global__ __launch_bounds__(256) void gate_kernel(
    const unsigned short* __restrict__ semb,
    const unsigned short* __restrict__ ctxb,
    const unsigned short* __restrict__ tempc,
    void* __restrict__ dout, const int* __restrict__ flag)
{
    int i = blockIdx.x * 256 + threadIdx.x;   // [0, BL*D_)
    int row = i / D_, c = i - row * D_;
    float sa = softplusf(bf2f(semb[(size_t)row * 1536 + c]));
    float sp = tanhf(bf2f(semb[(size_t)row * 1536 + D_ + c])) * PI_F;
    float ca = softplusf(bf2f(ctxb[(size_t)row * 1536 + c]));
    float cp = tanhf(bf2f(ctxb[(size_t)row * 1536 + D_ + c])) * PI_F;
    float inter = sa * ca * cosf(sp - cp) * bf2f(tempc[0]);
    float g = 1.f / (1.f + expf(-inter));
    if (flag[0]) ((float*)dout)[(size_t)GOFF + i] = g;
    else         ((unsigned short*)dout)[(size_t)GOFF + i] = f2bf(g);
}

// ---------------- Pass A: per-chunk sums of k (x) v and k -------------------------
// qkvt layout: (BL, 2304) = [q_f 768 | k_f 768 | v 768]
__global__ __launch_bounds__(256) void chunk_sum_kernel(
    const unsigned short* __restrict__ qkvt,
    float* __restrict__ Msum, float* __restrict__ Zsum)
{
    int blk = blockIdx.x;                 // 0..383
    int bh = blk / NC, cc = blk - bh * NC;
    int b = bh / H_, h = bh - b * H_;
    int t = threadIdx.x, e = t & 63, g = t >> 6;
    int r = t >> 4, c4 = (t & 15) * 4;
    __shared__ __align__(16) float kb[1024], vb[1024];
    float S[16] = {}; float z[16] = {};
    size_t rowbase = (size_t)(b * L_ + cc * CHUNK);
    const unsigned short* kg = qkvt + rowbase * 2304 + D_ + h * 64;
    const unsigned short* vg = qkvt + rowbase * 2304 + 2 * D_ + h * 64;
    for (int t0 = 0; t0 < CHUNK; t0 += 16) {
        ushort4 kk4 = *(const ushort4*)&kg[(size_t)(t0 + r) * 2304 + c4];
        ushort4 vv4 = *(const ushort4*)&vg[(size_t)(t0 + r) * 2304 + c4];
        __syncthreads();
        kb[r * 64 + c4 + 0] = bf2f(kk4.x); kb[r * 64 + c4 + 1] = bf2f(kk4.y);
        kb[r * 64 + c4 + 2] = bf2f(kk4.z); kb[r * 64 + c4 + 3] = bf2f(kk4.w);
        vb[r * 64 + c4 + 0] = bf2f(vv4.x); vb[r * 64 + c4 + 1] = bf2f(vv4.y);
        vb[r * 64 + c4 + 2] = bf2f(vv4.z); vb[r * 64 + c4 + 3] = bf2f(vv4.w);
        __syncthreads();
        for (int lr = 0; lr < 16; lr++) {
            float ve = vb[lr * 64 + e];
            #pragma unroll
            for (int i4 = 0; i4 < 4; i4++) {
                float4 kf = *(const float4*)&kb[lr * 64 + g * 16 + i4 * 4];
                int i = i4 * 4;
                S[i + 0] += kf.x * ve; z[i + 0] += kf.x;
                S[i + 1] += kf.y * ve; z[i + 1] += kf.y;
                S[i + 2] += kf.z * ve; z[i + 2] += kf.z;
                S[i + 3] += kf.w * ve; z[i + 3] += kf.w;
            }
        }
    }
    float* mo = Msum + (size_t)blk * 4096;
    #pragma unroll
    for (int i = 0; i < 16; i++) mo[(g * 16 + i) * 64 + e] = S[i];
    if (e == 0) {
        float* zo = Zsum + (size_t)blk * 64;
        #pragma unroll
        for (int i = 0; i < 16; i++) zo[g * 16 + i] = z[i];
    }
}

// ---------------- Pass B: exclusive prefix over chunks (grid = BH) ----------------
__global__ __launch_bounds__(256) void prefix_kernel(
    float* __restrict__ Msum, float* __restrict__ Zsum)
{
    int bh = blockIdx.x, t = threadIdx.x;
    float run[16];
    #pragma unroll
    for (int j = 0; j < 16; j++) run[j] = 0.f;
    for (int c = 0; c < NC; c++) {
        float* p = Msum + ((size_t)bh * NC + c) * 4096 + t * 16;
        #pragma unroll
        for (int j = 0; j < 16; j += 4) {
            float4 v = *(float4*)&p[j];
            float4 o = make_float4(run[j], run[j + 1], run[j + 2], run[j + 3]);
            run[j] += v.x; run[j + 1] += v.y; run[j + 2] += v.z; run[j + 3] += v.w;
            *(float4*)&p[j] = o;
        }
    }
    if (t < 64) {
        float rz = 0.f;
        for (int c = 0; c < NC; c++) {
            float* pz = Zsum + ((size_t)bh * NC + c) * 64 + t;
            float v = *pz; *pz = rz; rz += v;
        }
    }
}

// ---------------- Pass C: within-chunk causal scan seeded by prefix ---------------
__global__ __launch_bounds__(256) void chunk_scan_kernel(
    const unsigned short* __restrict__ qkvt,
    const float* __restrict__ Msum, const float* __restrict__ Zsum,
    unsigned short* __restrict__ attnb)
{
    int blk = blockIdx.x;
    int bh = blk / NC, cc = blk - bh * NC;
    int b = bh / H_, h = bh - b * H_;
    int t = threadIdx.x, e = t & 63, g = t >> 6;
    int r = t >> 4, c4 = (t & 15) * 4;
    __shared__ __align__(16) float qb[1024], kb[1024], vb[1024];
    __shared__ float numred[256];
    __shared__ float denred[4];
    float S[16], z[16];
    const float* mp = Msum + (size_t)blk * 4096;
    const float* zp = Zsum + (size_t)blk * 64;
    #pragma unroll
    for (int i = 0; i < 16; i++) { S[i] = mp[(g * 16 + i) * 64 + e]; z[i] = zp[g * 16 + i]; }
    size_t rowbase = (size_t)(b * L_ + cc * CHUNK);
    const unsigned short* qg = qkvt + rowbase * 2304 + h * 64;
    const unsigned short* kg = qkvt + rowbase * 2304 + D_ + h * 64;
    const unsigned short* vg = qkvt + rowbase * 2304 + 2 * D_ + h * 64;
    unsigned short* abase = attnb + rowbase * D_ + h * 64;
    for (int t0 = 0; t0 < CHUNK; t0 += 16) {
        ushort4 qq4 = *(const ushort4*)&qg[(size_t)(t0 + r) * 2304 + c4];
        ushort4 kk4 = *(const ushort4*)&kg[(size_t)(t0 + r) * 2304 + c4];
        ushort4 vv4 = *(const ushort4*)&vg[(size_t)(t0 + r) * 2304 + c4];
        qb[r * 64 + c4 + 0] = bf2f(qq4.x); qb[r * 64 + c4 + 1] = bf2f(qq4.y);
        qb[r * 64 + c4 + 2] = bf2f(qq4.z); qb[r * 64 + c4 + 3] = bf2f(qq4.w);
        kb[r * 64 + c4 + 0] = bf2f(kk4.x); kb[r * 64 + c4 + 1] = bf2f(kk4.y);
        kb[r * 64 + c4 + 2] = bf2f(kk4.z); kb[r * 64 + c4 + 3] = bf2f(kk4.w);
        vb[r * 64 + c4 + 0] = bf2f(vv4.x); vb[r * 64 + c4 + 1] = bf2f(vv4.y);
        vb[r * 64 + c4 + 2] = bf2f(vv4.z); vb[r * 64 + c4 + 3] = bf2f(vv4.w);
        __syncthreads();
        for (int lr = 0; lr < 16; lr++) {
            float ve = vb[lr * 64 + e];
            float num = 0.f, den = 0.f;
            #pragma unroll
            for (int i4 = 0; i4 < 4; i4++) {
                float4 kf = *(const float4*)&kb[lr * 64 + g * 16 + i4 * 4];
                float4 qf = *(const float4*)&qb[lr * 64 + g * 16 + i4 * 4];
                int i = i4 * 4;
                S[i + 0] += kf.x * ve; num += qf.x * S[i + 0]; z[i + 0] += kf.x; den += qf.x * z[i + 0];
                S[i + 1] += kf.y * ve; num += qf.y * S[i + 1]; z[i + 1] += kf.y; den += qf.y * z[i + 1];
                S[i + 2] += kf.z * ve; num += qf.z * S[i + 2]; z[i + 2] += kf.z; den += qf.z * z[i + 2];
                S[i + 3] += kf.w * ve; num += qf.w * S[i + 3]; z[i + 3] += kf.w; den += qf.w * z[i + 3];
            }
            numred[t] = num;
            if (e == 0) denred[g] = den;
            __syncthreads();
            if (g == 0) {
                float nn = numred[e] + numred[64 + e] + numred[128 + e] + numred[192 + e];
                float dd = denred[0] + denred[1] + denred[2] + denred[3] + 1e-6f;
                abase[(size_t)(t0 + lr) * D_ + e] = f2bf(nn / dd);
            }
            __syncthreads();
        }
    }
}

extern "C" void kernel_launch(void* const* d_in, const int* in_sizes, int n_in,
                              void* d_out, int out_size, void* d_ws, size_t ws_size,
                              hipStream_t stream)
{
    // ---- workspace (~46 MB) ----
    char* w = (char*)d_ws;
    auto alloc = [&](size_t bytes) { void* p = (void*)w; w += (bytes + 255) & ~(size_t)255; return p; };
    int*            flagp   = (int*)alloc(256);
    unsigned short* x_c     = (unsigned short*)alloc((size_t)BL * D_ * 2);   // reused as attnb
    unsigned short* attnb   = x_c;
    unsigned short* xn      = (unsigned short*)alloc((size_t)BL * D_ * 2);
    unsigned short* WqkvT   = (unsigned short*)alloc((size_t)2304 * 768 * 2);
    unsigned short* WdT     = (unsigned short*)alloc((size_t)256 * 768 * 2);  // [WsdT;WcdT]
    unsigned short* WsuT    = (unsigned short*)alloc((size_t)1536 * 128 * 2);
    unsigned short* WcuT    = (unsigned short*)alloc((size_t)1536 * 128 * 2);
    unsigned short* WprojT  = (unsigned short*)alloc((size_t)768 * 768 * 2);
    unsigned short* bqkv_c  = (unsigned short*)alloc((size_t)2304 * 2);
    unsigned short* bproj_c = (unsigned short*)alloc((size_t)768 * 2);
    unsigned short* gamma_c = (unsigned short*)alloc((size_t)768 * 2);
    unsigned short* beta_c  = (unsigned short*)alloc((size_t)768 * 2);
    unsigned short* temp_c  = (unsigned short*)alloc(256);
    unsigned short* tdown   = (unsigned short*)alloc((size_t)BL * 256 * 2);  // [tsem|tctx]
    float*          Zsum    = (float*)alloc((size_t)BH * NC * 64 * 4);
    // region: semb+ctxb (gate phase)  ->  qkvt+Msum (attention phase). 25,165,824 B
    char* region = (char*)alloc((size_t)BL * 1536 * 2 * 2);
    unsigned short* semb = (unsigned short*)region;
    unsigned short* ctxb = (unsigned short*)(region + (size_t)BL * 1536 * 2);
    unsigned short* qkvt = (unsigned short*)region;                       // BL*2304 bf16
    float*          Msum = (float*)(region + (size_t)BL * 2304 * 2);      // BH*NC*4096 f32

    dim3 blk(256);
    // 0. dtype detect + canonicalize
    detect_kernel<<<1, blk, 0, stream>>>((const unsigned short*)d_in[0], flagp);
    convert_kernel<<<(BL * D_ + 255) / 256, blk, 0, stream>>>(d_in[0], x_c, BL * D_, flagp);
    transpose_convert_kernel<<<dim3(2304 / 32, 768 / 32), blk, 0, stream>>>(d_in[1], WqkvT, 768, 2304, flagp);
    convert_kernel<<<(2304 + 255) / 256, blk, 0, stream>>>(d_in[2], bqkv_c, 2304, flagp);
    transpose_convert_kernel<<<dim3(128 / 32, 768 / 32), blk, 0, stream>>>(d_in[3], WdT, 768, 128, flagp);
    transpose_convert_kernel<<<dim3(1536 / 32, 128 / 32), blk, 0, stream>>>(d_in[4], WsuT, 128, 1536, flagp);
    transpose_convert_kernel<<<dim3(128 / 32, 768 / 32), blk, 0, stream>>>(d_in[5], WdT + (size_t)128 * 768, 768, 128, flagp);
    transpose_convert_kernel<<<dim3(1536 / 32, 128 / 32), blk, 0, stream>>>(d_in[6], WcuT, 128, 1536, flagp);
    convert_kernel<<<1, blk, 0, stream>>>(d_in[7], temp_c, 1, flagp);
    transpose_convert_kernel<<<dim3(768 / 32, 768 / 32), blk, 0, stream>>>(d_in[8], WprojT, 768, 768, flagp);
    convert_kernel<<<(768 + 255) / 256, blk, 0, stream>>>(d_in[9], bproj_c, 768, flagp);
    convert_kernel<<<(768 + 255) / 256, blk, 0, stream>>>(d_in[10], gamma_c, 768, flagp);
    convert_kernel<<<(768 + 255) / 256, blk, 0, stream>>>(d_in[11], beta_c, 768, flagp);
    // 1. LayerNorm
    ln_kernel<<<BL, blk, 0, stream>>>(x_c, gamma_c, beta_c, xn);
    // 2. merged down-projections (silu): tdown = silu(x @ [Wsd|Wcd])
    mfma_gemm_kernel<1><<<dim3(2, 32), blk, 0, stream>>>(x_c, 768, WdT, nullptr, nullptr, tdown, flagp, 256, 768);
    // 3. up-projections: semb = tsem @ Wsu, ctxb = tctx @ Wcu
    mfma_gemm_kernel<0><<<dim3(12, 32), blk, 0, stream>>>(tdown, 256, WsuT, nullptr, nullptr, semb, flagp, 1536, 128);
    mfma_gemm_kernel<0><<<dim3(12, 32), blk, 0, stream>>>(tdown + 128, 256, WcuT, nullptr, nullptr, ctxb, flagp, 1536, 128);
    // 4. interference gate -> d_out gate region (flagged dtype)
    gate_kernel<<<(BL * D_) / 256, blk, 0, stream>>>(semb, ctxb, temp_c, d_out, flagp);
    // 5. qkv GEMM with fused elu/gate epilogue (overwrites semb/ctxb region)
    mfma_gemm_kernel<2><<<dim3(18, 32), blk, 0, stream>>>(xn, 768, WqkvT, bqkv_c, d_out, qkvt, flagp, 2304, 768);
    // 6. chunked causal linear attention (single combined pass, 384 blocks)
    chunk_sum_kernel<<<BH * NC, blk, 0, stream>>>(qkvt, Msum, Zsum);
    prefix_kernel<<<BH, blk, 0, stream>>>(Msum, Zsum);
    chunk_scan_kernel<<<BH * NC, blk, 0, stream>>>(qkvt, Msum, Zsum, attnb);
    // 7. output projection (flagged store)
    mfma_gemm_kernel<3><<<dim3(6, 32), blk, 0, stream>>>(attnb, 768, WprojT, bproj_c, nullptr, d_out, flagp, 768, 768);
}

// Round 5
// 330.571 us; speedup vs baseline: 2.8528x; 1.2282x over previous
//
#include <hip/hip_runtime.h>

#define B_    2
#define L_    2048
#define D_    768
#define H_    12
#define BL    4096      // B_*L_
#define BH    24        // B_*H_
#define CHUNK 128
#define NC    16        // L_/CHUNK
#define GOFF  3145728   // element offset of gate output within d_out
#define PI_F  3.14159265358979f

typedef __bf16 bf16x8 __attribute__((ext_vector_type(8)));
typedef float  f32x4  __attribute__((ext_vector_type(4)));
typedef unsigned short us8 __attribute__((ext_vector_type(8)));

__device__ __forceinline__ float bf2f(unsigned short u) {
    return __uint_as_float(((unsigned int)u) << 16);
}
__device__ __forceinline__ unsigned short f2bf(float f) {
    unsigned int u = __float_as_uint(f);
    unsigned int r = (u + 0x7fffu + ((u >> 16) & 1u)) >> 16;
    return (unsigned short)r;
}
__device__ __forceinline__ float softplusf(float x) {
    return x > 20.f ? x : log1pf(expf(x));
}

// ---------------- dtype detector ----------------
__global__ __launch_bounds__(256) void detect_kernel(const unsigned short* __restrict__ x,
                                                     int* __restrict__ flag)
{
    __shared__ int cnt;
    if (threadIdx.x == 0) cnt = 0;
    __syncthreads();
    int c = 0;
    #pragma unroll
    for (int i = 0; i < 16; i++) {
        unsigned short u = x[threadIdx.x * 16 + i];
        int e = (u >> 7) & 0xff;
        if (e < 100 || e > 140) c++;
    }
    atomicAdd(&cnt, c);
    __syncthreads();
    if (threadIdx.x == 0) flag[0] = (cnt > 512) ? 1 : 0;   // 1 = inputs are fp32
}

// ---------------- mega convert: x + all small vectors -> bf16 ----------------
__global__ __launch_bounds__(256) void convert_mega_kernel(
    const void* __restrict__ sx, unsigned short* __restrict__ dx,
    const void* __restrict__ s1, unsigned short* __restrict__ d1,   // bqkv 2304
    const void* __restrict__ s2, unsigned short* __restrict__ d2,   // bproj 768
    const void* __restrict__ s3, unsigned short* __restrict__ d3,   // gamma 768
    const void* __restrict__ s4, unsigned short* __restrict__ d4,   // beta 768
    const void* __restrict__ s5, unsigned short* __restrict__ d5,   // temp 1
    const int* __restrict__ flag)
{
    int id = blockIdx.x, t = threadIdx.x;
    int fl = flag[0];
    const void* src; unsigned short* dst; int n, base;
    if (id < 12288)      { src = sx; dst = dx; n = BL * D_; base = id * 256; }
    else if (id < 12297) { src = s1; dst = d1; n = 2304; base = (id - 12288) * 256; }
    else if (id < 12300) { src = s2; dst = d2; n = 768;  base = (id - 12297) * 256; }
    else if (id < 12303) { src = s3; dst = d3; n = 768;  base = (id - 12300) * 256; }
    else if (id < 12306) { src = s4; dst = d4; n = 768;  base = (id - 12303) * 256; }
    else                 { src = s5; dst = d5; n = 1;    base = 0; }
    int i = base + t;
    if (i < n) dst[i] = fl ? f2bf(((const float*)src)[i]) : ((const unsigned short*)src)[i];
}

// ---------------- mega transpose: all 6 weights (K x N) -> (N x K) bf16 -----------
__global__ __launch_bounds__(256) void transpose_mega_kernel(
    const void* __restrict__ s0, unsigned short* __restrict__ dq,   // Wqkv 768x2304
    const void* __restrict__ s1, unsigned short* __restrict__ dd,   // Wsd 768x128 -> WdT[0]
    const void* __restrict__ s2, unsigned short* __restrict__ dsu,  // Wsu 128x1536
    const void* __restrict__ s3,                                    // Wcd 768x128 -> WdT[128*768]
    const void* __restrict__ s4, unsigned short* __restrict__ dcu,  // Wcu 128x1536
    const void* __restrict__ s5, unsigned short* __restrict__ dp,   // Wproj 768x768
    const int* __restrict__ flag)
{
    __shared__ unsigned short tile[32][33];
    int id = blockIdx.x;
    const void* src; unsigned short* dst; int K, N, tid;
    if (id < 1728)      { src = s0; dst = dq;  K = 768; N = 2304; tid = id; }
    else if (id < 1824) { src = s1; dst = dd;  K = 768; N = 128;  tid = id - 1728; }
    else if (id < 2016) { src = s2; dst = dsu; K = 128; N = 1536; tid = id - 1824; }
    else if (id < 2112) { src = s3; dst = dd + (size_t)128 * 768; K = 768; N = 128; tid = id - 2016; }
    else if (id < 2304) { src = s4; dst = dcu; K = 128; N = 1536; tid = id - 2112; }
    else                { src = s5; dst = dp;  K = 768; N = 768;  tid = id - 2304; }
    int tn = N / 32;
    int by = (tid / tn) * 32, bx = (tid % tn) * 32;
    int tx = threadIdx.x & 31, tyb = threadIdx.x >> 5;
    int fl = flag[0];
    #pragma unroll
    for (int i = 0; i < 4; i++) {
        int k = by + tyb * 4 + i, n = bx + tx;
        size_t off = (size_t)k * N + n;
        tile[tyb * 4 + i][tx] = fl ? f2bf(((const float*)src)[off]) : ((const unsigned short*)src)[off];
    }
    __syncthreads();
    #pragma unroll
    for (int i = 0; i < 4; i++) {
        int n = bx + tyb * 4 + i, k = by + tx;
        dst[(size_t)n * K + k] = tile[tx][tyb * 4 + i];
    }
}

// ---------------- LayerNorm ----------------
__global__ __launch_bounds__(256) void ln_kernel(
    const unsigned short* __restrict__ x,
    const unsigned short* __restrict__ gamma,
    const unsigned short* __restrict__ beta,
    unsigned short* __restrict__ xn)
{
    int row = blockIdx.x, t = threadIdx.x;
    const unsigned short* xr = x + (size_t)row * D_;
    float v[3];
    #pragma unroll
    for (int j = 0; j < 3; j++) v[j] = bf2f(xr[t + j * 256]);
    __shared__ float red[8];
    float s = v[0] + v[1] + v[2];
    #pragma unroll
    for (int m = 32; m >= 1; m >>= 1) s += __shfl_xor(s, m, 64);
    int wid = t >> 6;
    if ((t & 63) == 0) red[wid] = s;
    __syncthreads();
    float mean = (red[0] + red[1] + red[2] + red[3]) * (1.f / 768.f);
    float s2 = 0.f;
    #pragma unroll
    for (int j = 0; j < 3; j++) { float d = v[j] - mean; s2 += d * d; }
    #pragma unroll
    for (int m = 32; m >= 1; m >>= 1) s2 += __shfl_xor(s2, m, 64);
    if ((t & 63) == 0) red[4 + wid] = s2;
    __syncthreads();
    float var = (red[4] + red[5] + red[6] + red[7]) * (1.f / 768.f);
    float rs = rsqrtf(var + 1e-5f);
    #pragma unroll
    for (int j = 0; j < 3; j++) {
        int c = t + j * 256;
        float o = (v[j] - mean) * rs * bf2f(gamma[c]) + bf2f(beta[c]);
        xn[(size_t)row * D_ + c] = f2bf(o);
    }
}

// ---------------- MFMA GEMM v2: XCD swizzle, BK=64, coalesced LDS-transposed store
// A: 4096 x K (lda). BT: N x K. 128x128 tile, 4 waves, 4x4 mfma_16x16x32 per wave.
// EPI: 0 bias, 1 silu, 2 qkv transform, 3 flagged final store
template<int EPI>
__global__ __launch_bounds__(256) void mfma_gemm_kernel(
    const unsigned short* __restrict__ A, int lda,
    const unsigned short* __restrict__ BT,
    const unsigned short* __restrict__ bias,
    const void* __restrict__ gate,
    void* __restrict__ outp,
    const int* __restrict__ flag,
    int N, int K)
{
    __shared__ unsigned short sbuf[2 * 128 * 72];   // As | Bs ; Cs overlays As
    unsigned short* As = sbuf;
    unsigned short* Bs = sbuf + 128 * 72;
    unsigned short* Cs = sbuf;                       // 128*136 = 17408 <= 18432

    // XCD swizzle: strip = flat%8 owns a contiguous band of row-blocks
    int f = blockIdx.y * gridDim.x + blockIdx.x;
    int rps = gridDim.y >> 3;                        // gridDim.y divisible by 8
    int strip = f & 7, within = f >> 3;
    int by = strip * rps + (within % rps);
    int bx = within / rps;
    int m0 = by * 128, n0 = bx * 128;

    int t = threadIdx.x;
    int lane = t & 63, wave = t >> 6, quad = lane >> 4, l16 = lane & 15;
    int wm = (wave & 1) * 64, wn = (wave >> 1) * 64;
    int lr = t >> 1, lc = (t & 1) * 32;
    const unsigned short* Ap = A + (size_t)(m0 + lr) * lda + lc;
    const unsigned short* Bp = BT + (size_t)(n0 + lr) * K + lc;

    f32x4 acc[4][4];
    #pragma unroll
    for (int i = 0; i < 4; i++)
        #pragma unroll
        for (int j = 0; j < 4; j++) acc[i][j] = (f32x4){0.f, 0.f, 0.f, 0.f};

    for (int k0 = 0; k0 < K; k0 += 64) {
        us8 a[4], b[4];
        #pragma unroll
        for (int c = 0; c < 4; c++) {
            a[c] = *(const us8*)&Ap[k0 + c * 8];
            b[c] = *(const us8*)&Bp[k0 + c * 8];
        }
        __syncthreads();
        #pragma unroll
        for (int c = 0; c < 4; c++) {
            *(us8*)&As[lr * 72 + lc + c * 8] = a[c];
            *(us8*)&Bs[lr * 72 + lc + c * 8] = b[c];
        }
        __syncthreads();
        #pragma unroll
        for (int ks = 0; ks < 2; ks++) {
            bf16x8 af[4], bfr[4];
            #pragma unroll
            for (int i = 0; i < 4; i++)
                af[i] = *(const bf16x8*)&As[(wm + i * 16 + l16) * 72 + ks * 32 + quad * 8];
            #pragma unroll
            for (int j = 0; j < 4; j++)
                bfr[j] = *(const bf16x8*)&Bs[(wn + j * 16 + l16) * 72 + ks * 32 + quad * 8];
            #pragma unroll
            for (int i = 0; i < 4; i++)
                #pragma unroll
                for (int j = 0; j < 4; j++)
                    acc[i][j] = __builtin_amdgcn_mfma_f32_16x16x32_bf16(af[i], bfr[j], acc[i][j], 0, 0, 0);
        }
    }

    int fl = (EPI >= 2) ? flag[0] : 0;
    __syncthreads();                                 // LDS reads done; Cs overlays As
    #pragma unroll
    for (int j = 0; j < 4; j++) {
        int col = n0 + wn + j * 16 + l16;
        float bv = bias ? bf2f(bias[col]) : 0.f;
        #pragma unroll
        for (int i = 0; i < 4; i++) {
            #pragma unroll
            for (int r = 0; r < 4; r++) {
                int row = m0 + wm + i * 16 + quad * 4 + r;
                float v = acc[i][j][r] + bv;
                if (EPI == 1) v = v / (1.f + expf(-v));
                if (EPI == 2) {
                    if (col < D_) {
                        v = v > 0.f ? v + 1.f : expf(v);
                    } else if (col < 2 * D_) {
                        size_t go = (size_t)GOFF + (size_t)row * D_ + (col - D_);
                        float gg = fl ? ((const float*)gate)[go]
                                      : bf2f(((const unsigned short*)gate)[go]);
                        v *= (1.f + gg);
                        v = v > 0.f ? v + 1.f : expf(v);
                    }
                }
                if (EPI == 3 && fl) {
                    ((float*)outp)[(size_t)row * N + col] = v;   // 64B-aligned segments
                } else {
                    Cs[(wm + i * 16 + quad * 4 + r) * 136 + wn + j * 16 + l16] = f2bf(v);
                }
            }
        }
    }
    if (!(EPI == 3 && fl)) {
        __syncthreads();
        #pragma unroll
        for (int p = 0; p < 8; p++) {
            int idx = p * 256 + t;
            int row = idx >> 4, cc = (idx & 15) * 8;
            *(us8*)&((unsigned short*)outp)[(size_t)(m0 + row) * N + n0 + cc] =
                *(const us8*)&Cs[row * 136 + cc];
        }
    }
}

// ---------------- Fused up-projections + interference gate (MFMA) ----------------
// Block: 64 rows x 64 gate-cols. Wave w computes product w (sem_amp/sem_phase/
// ctx_amp/ctx_phase) 64x64 over K=128, exchange via LDS, combine elementwise.
__global__ __launch_bounds__(256) void gate_mfma_kernel(
    const unsigned short* __restrict__ tdown,   // BL x 256 = [tsem|tctx]
    const unsigned short* __restrict__ WsuT,    // 1536 x 128
    const unsigned short* __restrict__ WcuT,    // 1536 x 128
    const unsigned short* __restrict__ tempc,
    void* __restrict__ dout, const int* __restrict__ flag)
{
    __shared__ unsigned short gbuf[4 * 64 * 68];    // staging 6*64*40=15360 < 17408
    int f = blockIdx.y * gridDim.x + blockIdx.x;    // grid 12 x 64
    int rps = gridDim.y >> 3;
    int strip = f & 7, within = f >> 3;
    int by = strip * rps + (within % rps);
    int bx = within / rps;
    int m0 = by * 64, c0 = bx * 64;

    int t = threadIdx.x;
    int lane = t & 63, wave = t >> 6, quad = lane >> 4, l16 = lane & 15;
    int tr = t >> 2, tc = (t & 3) * 8;
    f32x4 acc[4][4];
    #pragma unroll
    for (int i = 0; i < 4; i++)
        #pragma unroll
        for (int j = 0; j < 4; j++) acc[i][j] = (f32x4){0.f, 0.f, 0.f, 0.f};

    int Atile = wave >> 1, Btile = 2 + wave;
    for (int k0 = 0; k0 < 128; k0 += 32) {
        us8 v0 = *(const us8*)&tdown[(size_t)(m0 + tr) * 256 + k0 + tc];
        us8 v1 = *(const us8*)&tdown[(size_t)(m0 + tr) * 256 + 128 + k0 + tc];
        us8 v2 = *(const us8*)&WsuT[(size_t)(c0 + tr) * 128 + k0 + tc];
        us8 v3 = *(const us8*)&WsuT[(size_t)(768 + c0 + tr) * 128 + k0 + tc];
        us8 v4 = *(const us8*)&WcuT[(size_t)(c0 + tr) * 128 + k0 + tc];
        us8 v5 = *(const us8*)&WcuT[(size_t)(768 + c0 + tr) * 128 + k0 + tc];
        __syncthreads();
        *(us8*)&gbuf[0 * 2560 + tr * 40 + tc] = v0;
        *(us8*)&gbuf[1 * 2560 + tr * 40 + tc] = v1;
        *(us8*)&gbuf[2 * 2560 + tr * 40 + tc] = v2;
        *(us8*)&gbuf[3 * 2560 + tr * 40 + tc] = v3;
        *(us8*)&gbuf[4 * 2560 + tr * 40 + tc] = v4;
        *(us8*)&gbuf[5 * 2560 + tr * 40 + tc] = v5;
        __syncthreads();
        bf16x8 af[4], bfr[4];
        #pragma unroll
        for (int i = 0; i < 4; i++)
            af[i] = *(const bf16x8*)&gbuf[Atile * 2560 + (i * 16 + l16) * 40 + quad * 8];
        #pragma unroll
        for (int j = 0; j < 4; j++)
            bfr[j] = *(const bf16x8*)&gbuf[Btile * 2560 + (j * 16 + l16) * 40 + quad * 8];
        #pragma unroll
        for (int i = 0; i < 4; i++)
            #pragma unroll
            for (int j = 0; j < 4; j++)
                acc[i][j] = __builtin_amdgcn_mfma_f32_16x16x32_bf16(af[i], bfr[j], acc[i][j], 0, 0, 0);
    }
    __syncthreads();
    // deposit product tiles (bf16) for exchange
    #pragma unroll
    for (int i = 0; i < 4; i++)
        #pragma unroll
        for (int j = 0; j < 4; j++)
            #pragma unroll
            for (int r = 0; r < 4; r++)
                gbuf[wave * 4352 + (i * 16 + quad * 4 + r) * 68 + j * 16 + l16] = f2bf(acc[i][j][r]);
    __syncthreads();
    float tempv = bf2f(tempc[0]);
    int fl = flag[0];
    #pragma unroll
    for (int p = 0; p < 16; p++) {
        int idx = p * 256 + t;
        int row = idx >> 6, col = idx & 63;
        float sa = softplusf(bf2f(gbuf[0 * 4352 + row * 68 + col]));
        float sp = tanhf(bf2f(gbuf[1 * 4352 + row * 68 + col])) * PI_F;
        float ca = softplusf(bf2f(gbuf[2 * 4352 + row * 68 + col]));
        float cp = tanhf(bf2f(gbuf[3 * 4352 + row * 68 + col])) * PI_F;
        float inter = sa * ca * cosf(sp - cp) * tempv;
        float g = 1.f / (1.f + expf(-inter));
        size_t off = (size_t)GOFF + (size_t)(m0 + row) * D_ + c0 + col;
        if (fl) ((float*)dout)[off] = g;
        else    ((unsigned short*)dout)[off] = f2bf(g);
    }
}

// ---------------- Pass A: per-chunk sums of k (x) v and k -------------------------
__global__ __launch_bounds__(256) void chunk_sum_kernel(
    const unsigned short* __restrict__ qkvt,
    float* __restrict__ Msum, float* __restrict__ Zsum)
{
    int blk = blockIdx.x;
    int bh = blk / NC, cc = blk - bh * NC;
    int b = bh / H_, h = bh - b * H_;
    int t = threadIdx.x, e = t & 63, g = t >> 6;
    int r = t >> 4, c4 = (t & 15) * 4;
    __shared__ __align__(16) float kb[1024], vb[1024];
    float S[16] = {}; float z[16] = {};
    size_t rowbase = (size_t)(b * L_ + cc * CHUNK);
    const unsigned short* kg = qkvt + rowbase * 2304 + D_ + h * 64;
    const unsigned short* vg = qkvt + rowbase * 2304 + 2 * D_ + h * 64;
    for (int t0 = 0; t0 < CHUNK; t0 += 16) {
        ushort4 kk4 = *(const ushort4*)&kg[(size_t)(t0 + r) * 2304 + c4];
        ushort4 vv4 = *(const ushort4*)&vg[(size_t)(t0 + r) * 2304 + c4];
        __syncthreads();
        kb[r * 64 + c4 + 0] = bf2f(kk4.x); kb[r * 64 + c4 + 1] = bf2f(kk4.y);
        kb[r * 64 + c4 + 2] = bf2f(kk4.z); kb[r * 64 + c4 + 3] = bf2f(kk4.w);
        vb[r * 64 + c4 + 0] = bf2f(vv4.x); vb[r * 64 + c4 + 1] = bf2f(vv4.y);
        vb[r * 64 + c4 + 2] = bf2f(vv4.z); vb[r * 64 + c4 + 3] = bf2f(vv4.w);
        __syncthreads();
        for (int lr = 0; lr < 16; lr++) {
            float ve = vb[lr * 64 + e];
            #pragma unroll
            for (int i4 = 0; i4 < 4; i4++) {
                float4 kf = *(const float4*)&kb[lr * 64 + g * 16 + i4 * 4];
                int i = i4 * 4;
                S[i + 0] += kf.x * ve; z[i + 0] += kf.x;
                S[i + 1] += kf.y * ve; z[i + 1] += kf.y;
                S[i + 2] += kf.z * ve; z[i + 2] += kf.z;
                S[i + 3] += kf.w * ve; z[i + 3] += kf.w;
            }
        }
    }
    float* mo = Msum + (size_t)blk * 4096;
    #pragma unroll
    for (int i = 0; i < 16; i++) mo[(g * 16 + i) * 64 + e] = S[i];
    if (e == 0) {
        float* zo = Zsum + (size_t)blk * 64;
        #pragma unroll
        for (int i = 0; i < 16; i++) zo[g * 16 + i] = z[i];
    }
}

// ---------------- Pass B: exclusive prefix over chunks ----------------
__global__ __launch_bounds__(256) void prefix_kernel(
    float* __restrict__ Msum, float* __restrict__ Zsum)
{
    int bh = blockIdx.x, t = threadIdx.x;
    float run[16];
    #pragma unroll
    for (int j = 0; j < 16; j++) run[j] = 0.f;
    for (int c = 0; c < NC; c++) {
        float* p = Msum + ((size_t)bh * NC + c) * 4096 + t * 16;
        #pragma unroll
        for (int j = 0; j < 16; j += 4) {
            float4 v = *(float4*)&p[j];
            float4 o = make_float4(run[j], run[j + 1], run[j + 2], run[j + 3]);
            run[j] += v.x; run[j + 1] += v.y; run[j + 2] += v.z; run[j + 3] += v.w;
            *(float4*)&p[j] = o;
        }
    }
    if (t < 64) {
        float rz = 0.f;
        for (int c = 0; c < NC; c++) {
            float* pz = Zsum + ((size_t)bh * NC + c) * 64 + t;
            float v = *pz; *pz = rz; rz += v;
        }
    }
}

// ---------------- Pass C: within-chunk causal scan ----------------
__global__ __launch_bounds__(256) void chunk_scan_kernel(
    const unsigned short* __restrict__ qkvt,
    const float* __restrict__ Msum, const float* __restrict__ Zsum,
    unsigned short* __restrict__ attnb)
{
    int blk = blockIdx.x;
    int bh = blk / NC, cc = blk - bh * NC;
    int b = bh / H_, h = bh - b * H_;
    int t = threadIdx.x, e = t & 63, g = t >> 6;
    int r = t >> 4, c4 = (t & 15) * 4;
    __shared__ __align__(16) float qb[1024], kb[1024], vb[1024];
    __shared__ float numred[256];
    __shared__ float denred[4];
    float S[16], z[16];
    const float* mp = Msum + (size_t)blk * 4096;
    const float* zp = Zsum + (size_t)blk * 64;
    #pragma unroll
    for (int i = 0; i < 16; i++) { S[i] = mp[(g * 16 + i) * 64 + e]; z[i] = zp[g * 16 + i]; }
    size_t rowbase = (size_t)(b * L_ + cc * CHUNK);
    const unsigned short* qg = qkvt + rowbase * 2304 + h * 64;
    const unsigned short* kg = qkvt + rowbase * 2304 + D_ + h * 64;
    const unsigned short* vg = qkvt + rowbase * 2304 + 2 * D_ + h * 64;
    unsigned short* abase = attnb + rowbase * D_ + h * 64;
    for (int t0 = 0; t0 < CHUNK; t0 += 16) {
        ushort4 qq4 = *(const ushort4*)&qg[(size_t)(t0 + r) * 2304 + c4];
        ushort4 kk4 = *(const ushort4*)&kg[(size_t)(t0 + r) * 2304 + c4];
        ushort4 vv4 = *(const ushort4*)&vg[(size_t)(t0 + r) * 2304 + c4];
        qb[r * 64 + c4 + 0] = bf2f(qq4.x); qb[r * 64 + c4 + 1] = bf2f(qq4.y);
        qb[r * 64 + c4 + 2] = bf2f(qq4.z); qb[r * 64 + c4 + 3] = bf2f(qq4.w);
        kb[r * 64 + c4 + 0] = bf2f(kk4.x); kb[r * 64 + c4 + 1] = bf2f(kk4.y);
        kb[r * 64 + c4 + 2] = bf2f(kk4.z); kb[r * 64 + c4 + 3] = bf2f(kk4.w);
        vb[r * 64 + c4 + 0] = bf2f(vv4.x); vb[r * 64 + c4 + 1] = bf2f(vv4.y);
        vb[r * 64 + c4 + 2] = bf2f(vv4.z); vb[r * 64 + c4 + 3] = bf2f(vv4.w);
        __syncthreads();
        for (int lr = 0; lr < 16; lr++) {
            float ve = vb[lr * 64 + e];
            float num = 0.f, den = 0.f;
            #pragma unroll
            for (int i4 = 0; i4 < 4; i4++) {
                float4 kf = *(const float4*)&kb[lr * 64 + g * 16 + i4 * 4];
                float4 qf = *(const float4*)&qb[lr * 64 + g * 16 + i4 * 4];
                int i = i4 * 4;
                S[i + 0] += kf.x * ve; num += qf.x * S[i + 0]; z[i + 0] += kf.x; den += qf.x * z[i + 0];
                S[i + 1] += kf.y * ve; num += qf.y * S[i + 1]; z[i + 1] += kf.y; den += qf.y * z[i + 1];
                S[i + 2] += kf.z * ve; num += qf.z * S[i + 2]; z[i + 2] += kf.z; den += qf.z * z[i + 2];
                S[i + 3] += kf.w * ve; num += qf.w * S[i + 3]; z[i + 3] += kf.w; den += qf.w * z[i + 3];
            }
            numred[t] = num;
            if (e == 0) denred[g] = den;
            __syncthreads();
            if (g == 0) {
                float nn = numred[e] + numred[64 + e] + numred[128 + e] + numred[192 + e];
                float dd = denred[0] + denred[1] + denred[2] + denred[3] + 1e-6f;
                abase[(size_t)(t0 + lr) * D_ + e] = f2bf(nn / dd);
            }
            __syncthreads();
        }
    }
}

extern "C" void kernel_launch(void* const* d_in, const int* in_sizes, int n_in,
                              void* d_out, int out_size, void* d_ws, size_t ws_size,
                              hipStream_t stream)
{
    char* w = (char*)d_ws;
    auto alloc = [&](size_t bytes) { void* p = (void*)w; w += (bytes + 255) & ~(size_t)255; return p; };
    int*            flagp   = (int*)alloc(256);
    unsigned short* x_c     = (unsigned short*)alloc((size_t)BL * D_ * 2);   // reused as attnb
    unsigned short* attnb   = x_c;
    unsigned short* xn      = (unsigned short*)alloc((size_t)BL * D_ * 2);
    unsigned short* WqkvT   = (unsigned short*)alloc((size_t)2304 * 768 * 2);
    unsigned short* WdT     = (unsigned short*)alloc((size_t)256 * 768 * 2);
    unsigned short* WsuT    = (unsigned short*)alloc((size_t)1536 * 128 * 2);
    unsigned short* WcuT    = (unsigned short*)alloc((size_t)1536 * 128 * 2);
    unsigned short* WprojT  = (unsigned short*)alloc((size_t)768 * 768 * 2);
    unsigned short* bqkv_c  = (unsigned short*)alloc((size_t)2304 * 2);
    unsigned short* bproj_c = (unsigned short*)alloc((size_t)768 * 2);
    unsigned short* gamma_c = (unsigned short*)alloc((size_t)768 * 2);
    unsigned short* beta_c  = (unsigned short*)alloc((size_t)768 * 2);
    unsigned short* temp_c  = (unsigned short*)alloc(256);
    unsigned short* tdown   = (unsigned short*)alloc((size_t)BL * 256 * 2);
    float*          Zsum    = (float*)alloc((size_t)BH * NC * 64 * 4);
    unsigned short* qkvt    = (unsigned short*)alloc((size_t)BL * 2304 * 2);
    float*          Msum    = (float*)alloc((size_t)BH * NC * 4096 * 4);

    dim3 blk(256);
    // 0. detect + canonicalize (2 mega-kernels)
    detect_kernel<<<1, blk, 0, stream>>>((const unsigned short*)d_in[0], flagp);
    convert_mega_kernel<<<12307, blk, 0, stream>>>(
        d_in[0], x_c, d_in[2], bqkv_c, d_in[9], bproj_c,
        d_in[10], gamma_c, d_in[11], beta_c, d_in[7], temp_c, flagp);
    transpose_mega_kernel<<<2880, blk, 0, stream>>>(
        d_in[1], WqkvT, d_in[3], WdT, d_in[4], WsuT,
        d_in[5], d_in[6], WcuT, d_in[8], WprojT, flagp);
    // 1. LayerNorm
    ln_kernel<<<BL, blk, 0, stream>>>(x_c, gamma_c, beta_c, xn);
    // 2. merged down-projections (silu)
    mfma_gemm_kernel<1><<<dim3(2, 32), blk, 0, stream>>>(x_c, 768, WdT, nullptr, nullptr, tdown, flagp, 256, 768);
    // 3. fused up-projections + gate -> d_out gate region
    gate_mfma_kernel<<<dim3(12, 64), blk, 0, stream>>>(tdown, WsuT, WcuT, temp_c, d_out, flagp);
    // 4. qkv GEMM with fused elu/gate epilogue
    mfma_gemm_kernel<2><<<dim3(18, 32), blk, 0, stream>>>(xn, 768, WqkvT, bqkv_c, d_out, qkvt, flagp, 2304, 768);
    // 5. chunked causal linear attention
    chunk_sum_kernel<<<BH * NC, blk, 0, stream>>>(qkvt, Msum, Zsum);
    prefix_kernel<<<BH, blk, 0, stream>>>(Msum, Zsum);
    chunk_scan_kernel<<<BH * NC, blk, 0, stream>>>(qkvt, Msum, Zsum, attnb);
    // 6. output projection (flagged store)
    mfma_gemm_kernel<3><<<dim3(6, 32), blk, 0, stream>>>(attnb, 768, WprojT, bproj_c, nullptr, d_out, flagp, 768, 768);
}

// Round 6
// 256.214 us; speedup vs baseline: 3.6807x; 1.2902x over previous
//
#include <hip/hip_runtime.h>

#define B_    2
#define L_    2048
#define D_    768
#define H_    12
#define BL    4096      // B_*L_
#define BH    24        // B_*H_
#define CHUNK 128
#define NC    16        // L_/CHUNK
#define GOFF  3145728   // element offset of gate output within d_out
#define PI_F  3.14159265358979f

typedef __bf16 bf16x8 __attribute__((ext_vector_type(8)));
typedef float  f32x4  __attribute__((ext_vector_type(4)));
typedef unsigned short us8 __attribute__((ext_vector_type(8)));

__device__ __forceinline__ float bf2f(unsigned short u) {
    return __uint_as_float(((unsigned int)u) << 16);
}
__device__ __forceinline__ unsigned short f2bf(float f) {
    unsigned int u = __float_as_uint(f);
    unsigned int r = (u + 0x7fffu + ((u >> 16) & 1u)) >> 16;
    return (unsigned short)r;
}
__device__ __forceinline__ float softplusf(float x) {
    return x > 20.f ? x : log1pf(expf(x));
}

// ---------------- dtype detector ----------------
__global__ __launch_bounds__(256) void detect_kernel(const unsigned short* __restrict__ x,
                                                     int* __restrict__ flag)
{
    __shared__ int cnt;
    if (threadIdx.x == 0) cnt = 0;
    __syncthreads();
    int c = 0;
    #pragma unroll
    for (int i = 0; i < 16; i++) {
        unsigned short u = x[threadIdx.x * 16 + i];
        int e = (u >> 7) & 0xff;
        if (e < 100 || e > 140) c++;
    }
    atomicAdd(&cnt, c);
    __syncthreads();
    if (threadIdx.x == 0) flag[0] = (cnt > 512) ? 1 : 0;   // 1 = inputs are fp32
}

// ---------------- mega convert: x + all small vectors -> bf16 ----------------
__global__ __launch_bounds__(256) void convert_mega_kernel(
    const void* __restrict__ sx, unsigned short* __restrict__ dx,
    const void* __restrict__ s1, unsigned short* __restrict__ d1,   // bqkv 2304
    const void* __restrict__ s2, unsigned short* __restrict__ d2,   // bproj 768
    const void* __restrict__ s3, unsigned short* __restrict__ d3,   // gamma 768
    const void* __restrict__ s4, unsigned short* __restrict__ d4,   // beta 768
    const void* __restrict__ s5, unsigned short* __restrict__ d5,   // temp 1
    const int* __restrict__ flag)
{
    int id = blockIdx.x, t = threadIdx.x;
    int fl = flag[0];
    const void* src; unsigned short* dst; int n, base;
    if (id < 12288)      { src = sx; dst = dx; n = BL * D_; base = id * 256; }
    else if (id < 12297) { src = s1; dst = d1; n = 2304; base = (id - 12288) * 256; }
    else if (id < 12300) { src = s2; dst = d2; n = 768;  base = (id - 12297) * 256; }
    else if (id < 12303) { src = s3; dst = d3; n = 768;  base = (id - 12300) * 256; }
    else if (id < 12306) { src = s4; dst = d4; n = 768;  base = (id - 12303) * 256; }
    else                 { src = s5; dst = d5; n = 1;    base = 0; }
    int i = base + t;
    if (i < n) dst[i] = fl ? f2bf(((const float*)src)[i]) : ((const unsigned short*)src)[i];
}

// ---------------- mega transpose: all 6 weights (K x N) -> (N x K) bf16 -----------
__global__ __launch_bounds__(256) void transpose_mega_kernel(
    const void* __restrict__ s0, unsigned short* __restrict__ dq,   // Wqkv 768x2304
    const void* __restrict__ s1, unsigned short* __restrict__ dd,   // Wsd 768x128 -> WdT[0]
    const void* __restrict__ s2, unsigned short* __restrict__ dsu,  // Wsu 128x1536
    const void* __restrict__ s3,                                    // Wcd 768x128 -> WdT[128*768]
    const void* __restrict__ s4, unsigned short* __restrict__ dcu,  // Wcu 128x1536
    const void* __restrict__ s5, unsigned short* __restrict__ dp,   // Wproj 768x768
    const int* __restrict__ flag)
{
    __shared__ unsigned short tile[32][33];
    int id = blockIdx.x;
    const void* src; unsigned short* dst; int K, N, tid;
    if (id < 1728)      { src = s0; dst = dq;  K = 768; N = 2304; tid = id; }
    else if (id < 1824) { src = s1; dst = dd;  K = 768; N = 128;  tid = id - 1728; }
    else if (id < 2016) { src = s2; dst = dsu; K = 128; N = 1536; tid = id - 1824; }
    else if (id < 2112) { src = s3; dst = dd + (size_t)128 * 768; K = 768; N = 128; tid = id - 2016; }
    else if (id < 2304) { src = s4; dst = dcu; K = 128; N = 1536; tid = id - 2112; }
    else                { src = s5; dst = dp;  K = 768; N = 768;  tid = id - 2304; }
    int tn = N / 32;
    int by = (tid / tn) * 32, bx = (tid % tn) * 32;
    int tx = threadIdx.x & 31, tyb = threadIdx.x >> 5;
    int fl = flag[0];
    #pragma unroll
    for (int i = 0; i < 4; i++) {
        int k = by + tyb * 4 + i, n = bx + tx;
        size_t off = (size_t)k * N + n;
        tile[tyb * 4 + i][tx] = fl ? f2bf(((const float*)src)[off]) : ((const unsigned short*)src)[off];
    }
    __syncthreads();
    #pragma unroll
    for (int i = 0; i < 4; i++) {
        int n = bx + tyb * 4 + i, k = by + tx;
        dst[(size_t)n * K + k] = tile[tx][tyb * 4 + i];
    }
}

// ---------------- LayerNorm ----------------
__global__ __launch_bounds__(256) void ln_kernel(
    const unsigned short* __restrict__ x,
    const unsigned short* __restrict__ gamma,
    const unsigned short* __restrict__ beta,
    unsigned short* __restrict__ xn)
{
    int row = blockIdx.x, t = threadIdx.x;
    const unsigned short* xr = x + (size_t)row * D_;
    float v[3];
    #pragma unroll
    for (int j = 0; j < 3; j++) v[j] = bf2f(xr[t + j * 256]);
    __shared__ float red[8];
    float s = v[0] + v[1] + v[2];
    #pragma unroll
    for (int m = 32; m >= 1; m >>= 1) s += __shfl_xor(s, m, 64);
    int wid = t >> 6;
    if ((t & 63) == 0) red[wid] = s;
    __syncthreads();
    float mean = (red[0] + red[1] + red[2] + red[3]) * (1.f / 768.f);
    float s2 = 0.f;
    #pragma unroll
    for (int j = 0; j < 3; j++) { float d = v[j] - mean; s2 += d * d; }
    #pragma unroll
    for (int m = 32; m >= 1; m >>= 1) s2 += __shfl_xor(s2, m, 64);
    if ((t & 63) == 0) red[4 + wid] = s2;
    __syncthreads();
    float var = (red[4] + red[5] + red[6] + red[7]) * (1.f / 768.f);
    float rs = rsqrtf(var + 1e-5f);
    #pragma unroll
    for (int j = 0; j < 3; j++) {
        int c = t + j * 256;
        float o = (v[j] - mean) * rs * bf2f(gamma[c]) + bf2f(beta[c]);
        xn[(size_t)row * D_ + c] = f2bf(o);
    }
}

// ---------------- MFMA GEMM v2 (unchanged from round 5) --------------------------
template<int EPI>
__global__ __launch_bounds__(256) void mfma_gemm_kernel(
    const unsigned short* __restrict__ A, int lda,
    const unsigned short* __restrict__ BT,
    const unsigned short* __restrict__ bias,
    const void* __restrict__ gate,
    void* __restrict__ outp,
    const int* __restrict__ flag,
    int N, int K)
{
    __shared__ unsigned short sbuf[2 * 128 * 72];
    unsigned short* As = sbuf;
    unsigned short* Bs = sbuf + 128 * 72;
    unsigned short* Cs = sbuf;

    int f = blockIdx.y * gridDim.x + blockIdx.x;
    int rps = gridDim.y >> 3;
    int strip = f & 7, within = f >> 3;
    int by = strip * rps + (within % rps);
    int bx = within / rps;
    int m0 = by * 128, n0 = bx * 128;

    int t = threadIdx.x;
    int lane = t & 63, wave = t >> 6, quad = lane >> 4, l16 = lane & 15;
    int wm = (wave & 1) * 64, wn = (wave >> 1) * 64;
    int lr = t >> 1, lc = (t & 1) * 32;
    const unsigned short* Ap = A + (size_t)(m0 + lr) * lda + lc;
    const unsigned short* Bp = BT + (size_t)(n0 + lr) * K + lc;

    f32x4 acc[4][4];
    #pragma unroll
    for (int i = 0; i < 4; i++)
        #pragma unroll
        for (int j = 0; j < 4; j++) acc[i][j] = (f32x4){0.f, 0.f, 0.f, 0.f};

    for (int k0 = 0; k0 < K; k0 += 64) {
        us8 a[4], b[4];
        #pragma unroll
        for (int c = 0; c < 4; c++) {
            a[c] = *(const us8*)&Ap[k0 + c * 8];
            b[c] = *(const us8*)&Bp[k0 + c * 8];
        }
        __syncthreads();
        #pragma unroll
        for (int c = 0; c < 4; c++) {
            *(us8*)&As[lr * 72 + lc + c * 8] = a[c];
            *(us8*)&Bs[lr * 72 + lc + c * 8] = b[c];
        }
        __syncthreads();
        #pragma unroll
        for (int ks = 0; ks < 2; ks++) {
            bf16x8 af[4], bfr[4];
            #pragma unroll
            for (int i = 0; i < 4; i++)
                af[i] = *(const bf16x8*)&As[(wm + i * 16 + l16) * 72 + ks * 32 + quad * 8];
            #pragma unroll
            for (int j = 0; j < 4; j++)
                bfr[j] = *(const bf16x8*)&Bs[(wn + j * 16 + l16) * 72 + ks * 32 + quad * 8];
            #pragma unroll
            for (int i = 0; i < 4; i++)
                #pragma unroll
                for (int j = 0; j < 4; j++)
                    acc[i][j] = __builtin_amdgcn_mfma_f32_16x16x32_bf16(af[i], bfr[j], acc[i][j], 0, 0, 0);
        }
    }

    int fl = (EPI >= 2) ? flag[0] : 0;
    __syncthreads();
    #pragma unroll
    for (int j = 0; j < 4; j++) {
        int col = n0 + wn + j * 16 + l16;
        float bv = bias ? bf2f(bias[col]) : 0.f;
        #pragma unroll
        for (int i = 0; i < 4; i++) {
            #pragma unroll
            for (int r = 0; r < 4; r++) {
                int row = m0 + wm + i * 16 + quad * 4 + r;
                float v = acc[i][j][r] + bv;
                if (EPI == 1) v = v / (1.f + expf(-v));
                if (EPI == 2) {
                    if (col < D_) {
                        v = v > 0.f ? v + 1.f : expf(v);
                    } else if (col < 2 * D_) {
                        size_t go = (size_t)GOFF + (size_t)row * D_ + (col - D_);
                        float gg = fl ? ((const float*)gate)[go]
                                      : bf2f(((const unsigned short*)gate)[go]);
                        v *= (1.f + gg);
                        v = v > 0.f ? v + 1.f : expf(v);
                    }
                }
                if (EPI == 3 && fl) {
                    ((float*)outp)[(size_t)row * N + col] = v;
                } else {
                    Cs[(wm + i * 16 + quad * 4 + r) * 136 + wn + j * 16 + l16] = f2bf(v);
                }
            }
        }
    }
    if (!(EPI == 3 && fl)) {
        __syncthreads();
        #pragma unroll
        for (int p = 0; p < 8; p++) {
            int idx = p * 256 + t;
            int row = idx >> 4, cc = (idx & 15) * 8;
            *(us8*)&((unsigned short*)outp)[(size_t)(m0 + row) * N + n0 + cc] =
                *(const us8*)&Cs[row * 136 + cc];
        }
    }
}

// ---------------- Fused up-projections + interference gate (unchanged) -----------
__global__ __launch_bounds__(256) void gate_mfma_kernel(
    const unsigned short* __restrict__ tdown,
    const unsigned short* __restrict__ WsuT,
    const unsigned short* __restrict__ WcuT,
    const unsigned short* __restrict__ tempc,
    void* __restrict__ dout, const int* __restrict__ flag)
{
    __shared__ unsigned short gbuf[4 * 64 * 68];
    int f = blockIdx.y * gridDim.x + blockIdx.x;
    int rps = gridDim.y >> 3;
    int strip = f & 7, within = f >> 3;
    int by = strip * rps + (within % rps);
    int bx = within / rps;
    int m0 = by * 64, c0 = bx * 64;

    int t = threadIdx.x;
    int lane = t & 63, wave = t >> 6, quad = lane >> 4, l16 = lane & 15;
    int tr = t >> 2, tc = (t & 3) * 8;
    f32x4 acc[4][4];
    #pragma unroll
    for (int i = 0; i < 4; i++)
        #pragma unroll
        for (int j = 0; j < 4; j++) acc[i][j] = (f32x4){0.f, 0.f, 0.f, 0.f};

    int Atile = wave >> 1, Btile = 2 + wave;
    for (int k0 = 0; k0 < 128; k0 += 32) {
        us8 v0 = *(const us8*)&tdown[(size_t)(m0 + tr) * 256 + k0 + tc];
        us8 v1 = *(const us8*)&tdown[(size_t)(m0 + tr) * 256 + 128 + k0 + tc];
        us8 v2 = *(const us8*)&WsuT[(size_t)(c0 + tr) * 128 + k0 + tc];
        us8 v3 = *(const us8*)&WsuT[(size_t)(768 + c0 + tr) * 128 + k0 + tc];
        us8 v4 = *(const us8*)&WcuT[(size_t)(c0 + tr) * 128 + k0 + tc];
        us8 v5 = *(const us8*)&WcuT[(size_t)(768 + c0 + tr) * 128 + k0 + tc];
        __syncthreads();
        *(us8*)&gbuf[0 * 2560 + tr * 40 + tc] = v0;
        *(us8*)&gbuf[1 * 2560 + tr * 40 + tc] = v1;
        *(us8*)&gbuf[2 * 2560 + tr * 40 + tc] = v2;
        *(us8*)&gbuf[3 * 2560 + tr * 40 + tc] = v3;
        *(us8*)&gbuf[4 * 2560 + tr * 40 + tc] = v4;
        *(us8*)&gbuf[5 * 2560 + tr * 40 + tc] = v5;
        __syncthreads();
        bf16x8 af[4], bfr[4];
        #pragma unroll
        for (int i = 0; i < 4; i++)
            af[i] = *(const bf16x8*)&gbuf[Atile * 2560 + (i * 16 + l16) * 40 + quad * 8];
        #pragma unroll
        for (int j = 0; j < 4; j++)
            bfr[j] = *(const bf16x8*)&gbuf[Btile * 2560 + (j * 16 + l16) * 40 + quad * 8];
        #pragma unroll
        for (int i = 0; i < 4; i++)
            #pragma unroll
            for (int j = 0; j < 4; j++)
                acc[i][j] = __builtin_amdgcn_mfma_f32_16x16x32_bf16(af[i], bfr[j], acc[i][j], 0, 0, 0);
    }
    __syncthreads();
    #pragma unroll
    for (int i = 0; i < 4; i++)
        #pragma unroll
        for (int j = 0; j < 4; j++)
            #pragma unroll
            for (int r = 0; r < 4; r++)
                gbuf[wave * 4352 + (i * 16 + quad * 4 + r) * 68 + j * 16 + l16] = f2bf(acc[i][j][r]);
    __syncthreads();
    float tempv = bf2f(tempc[0]);
    int fl = flag[0];
    #pragma unroll
    for (int p = 0; p < 16; p++) {
        int idx = p * 256 + t;
        int row = idx >> 6, col = idx & 63;
        float sa = softplusf(bf2f(gbuf[0 * 4352 + row * 68 + col]));
        float sp = tanhf(bf2f(gbuf[1 * 4352 + row * 68 + col])) * PI_F;
        float ca = softplusf(bf2f(gbuf[2 * 4352 + row * 68 + col]));
        float cp = tanhf(bf2f(gbuf[3 * 4352 + row * 68 + col])) * PI_F;
        float inter = sa * ca * cosf(sp - cp) * tempv;
        float g = 1.f / (1.f + expf(-inter));
        size_t off = (size_t)GOFF + (size_t)(m0 + row) * D_ + c0 + col;
        if (fl) ((float*)dout)[off] = g;
        else    ((unsigned short*)dout)[off] = f2bf(g);
    }
}

// ---------------- Pass A (MFMA): S_c = K^T . V_ext per (bh,chunk) -----------------
// K_T: 64x128 (d,s) stride 136. V_T: 80x128 (n,s) stride 136; row64 = ones.
// C[m=d_k][n]: n<64 -> Msum, n==64 -> Zsum.
__global__ __launch_bounds__(256) void chunk_sum_mfma_kernel(
    const unsigned short* __restrict__ qkvt,
    float* __restrict__ Msum, float* __restrict__ Zsum)
{
    __shared__ __align__(16) unsigned short KT[64 * 136];
    __shared__ __align__(16) unsigned short VT[80 * 136];
    int blk = blockIdx.x;
    int bh = blk / NC, cc = blk - bh * NC;
    int b = bh / H_, h = bh - b * H_;
    int t = threadIdx.x;
    int lane = t & 63, wave = t >> 6, quad = lane >> 4, l16 = lane & 15;
    int lr = t >> 1, lc = (t & 1) * 32;
    size_t rowbase = (size_t)(b * L_ + cc * CHUNK);
    const unsigned short* kg = qkvt + rowbase * 2304 + D_ + h * 64;
    const unsigned short* vg = qkvt + rowbase * 2304 + 2 * D_ + h * 64;
    #pragma unroll
    for (int c = 0; c < 4; c++) {
        us8 kv = *(const us8*)&kg[(size_t)lr * 2304 + lc + c * 8];
        us8 vv = *(const us8*)&vg[(size_t)lr * 2304 + lc + c * 8];
        #pragma unroll
        for (int ii = 0; ii < 8; ii++) {
            KT[(lc + c * 8 + ii) * 136 + lr] = kv[ii];
            VT[(lc + c * 8 + ii) * 136 + lr] = vv[ii];
        }
    }
    if (t < 128) VT[64 * 136 + t] = 0x3F80;   // ones row (bf16 1.0)
    __syncthreads();

    f32x4 acc[5];
    #pragma unroll
    for (int j = 0; j < 5; j++) acc[j] = (f32x4){0.f, 0.f, 0.f, 0.f};
    #pragma unroll
    for (int ks = 0; ks < 4; ks++) {
        bf16x8 a = *(const bf16x8*)&KT[(wave * 16 + l16) * 136 + ks * 32 + quad * 8];
        #pragma unroll
        for (int j = 0; j < 5; j++) {
            bf16x8 bv = *(const bf16x8*)&VT[(j * 16 + l16) * 136 + ks * 32 + quad * 8];
            acc[j] = __builtin_amdgcn_mfma_f32_16x16x32_bf16(a, bv, acc[j], 0, 0, 0);
        }
    }
    float* mo = Msum + (size_t)blk * 4096;
    #pragma unroll
    for (int j = 0; j < 4; j++)
        #pragma unroll
        for (int r = 0; r < 4; r++)
            mo[(wave * 16 + quad * 4 + r) * 64 + j * 16 + l16] = acc[j][r];
    if (l16 == 0) {
        #pragma unroll
        for (int r = 0; r < 4; r++)
            Zsum[(size_t)blk * 64 + wave * 16 + quad * 4 + r] = acc[4][r];
    }
}

// ---------------- Pass B: in-register exclusive prefix (grid = BH*4) --------------
__global__ __launch_bounds__(256) void prefix_kernel(
    float* __restrict__ Msum, float* __restrict__ Zsum)
{
    int blk = blockIdx.x;
    int bh = blk >> 2, qd = blk & 3;
    int t = threadIdx.x;
    size_t base = (size_t)bh * NC * 4096 + qd * 1024 + t * 4;
    float4 v[NC];
    #pragma unroll
    for (int c = 0; c < NC; c++) v[c] = *(const float4*)&Msum[base + (size_t)c * 4096];
    float4 run = make_float4(0.f, 0.f, 0.f, 0.f);
    #pragma unroll
    for (int c = 0; c < NC; c++) {
        float4 tmp = v[c];
        *(float4*)&Msum[base + (size_t)c * 4096] = run;
        run.x += tmp.x; run.y += tmp.y; run.z += tmp.z; run.w += tmp.w;
    }
    if (qd == 0 && t < 64) {
        float rz = 0.f;
        for (int c = 0; c < NC; c++) {
            float* pz = &Zsum[((size_t)bh * NC + c) * 64 + t];
            float vv = *pz; *pz = rz; rz += vv;
        }
    }
}

// ---------------- Pass C (MFMA): O = Q.S_prefix + tril(QK^T).V --------------------
// LDS: Qs[128x72]@0, Ks[128x72]@9216 ; P overlays Q+K (128x136) ; VT[80x136]@18432 ;
// Ss[80x72]@29312 (S_prefix^T: rows j=v-dim (64=z), cols d). Cout overlays P.
__global__ __launch_bounds__(256) void chunk_scan_mfma_kernel(
    const unsigned short* __restrict__ qkvt,
    const float* __restrict__ Msum, const float* __restrict__ Zsum,
    unsigned short* __restrict__ attnb)
{
    __shared__ __align__(16) unsigned short sbuf[35072];
    unsigned short* Qs = sbuf;                  // 128*72
    unsigned short* Ks = sbuf + 9216;           // 128*72
    unsigned short* Ps = sbuf;                  // 128*136 (overlay Q+K)
    unsigned short* VT = sbuf + 18432;          // 80*136
    unsigned short* Ss = sbuf + 29312;          // 80*72
    unsigned short* Cout = sbuf;                // 128*136 (overlay P)

    int blk = blockIdx.x;
    int bh = blk / NC, cc = blk - bh * NC;
    int b = bh / H_, h = bh - b * H_;
    int t = threadIdx.x;
    int lane = t & 63, wave = t >> 6, quad = lane >> 4, l16 = lane & 15;
    int wm = wave * 32;
    int lr = t >> 1, lc = (t & 1) * 32;
    size_t rowbase = (size_t)(b * L_ + cc * CHUNK);
    const unsigned short* qg = qkvt + rowbase * 2304 + h * 64;
    const unsigned short* kg = qkvt + rowbase * 2304 + D_ + h * 64;
    const unsigned short* vg = qkvt + rowbase * 2304 + 2 * D_ + h * 64;
    const float* mp = Msum + (size_t)blk * 4096;
    const float* zp = Zsum + (size_t)blk * 64;

    // ---- stage ----
    #pragma unroll
    for (int c = 0; c < 4; c++) {
        us8 qv = *(const us8*)&qg[(size_t)lr * 2304 + lc + c * 8];
        us8 kv = *(const us8*)&kg[(size_t)lr * 2304 + lc + c * 8];
        us8 vv = *(const us8*)&vg[(size_t)lr * 2304 + lc + c * 8];
        *(us8*)&Qs[lr * 72 + lc + c * 8] = qv;
        *(us8*)&Ks[lr * 72 + lc + c * 8] = kv;
        #pragma unroll
        for (int ii = 0; ii < 8; ii++)
            VT[(lc + c * 8 + ii) * 136 + lr] = vv[ii];
    }
    if (t < 128) VT[64 * 136 + t] = 0x3F80;     // ones row
    {
        int d = t & 63, jb = (t >> 6) * 16;
        #pragma unroll
        for (int g4 = 0; g4 < 4; g4++) {
            float4 sv = *(const float4*)&mp[d * 64 + jb + g4 * 4];
            Ss[(jb + g4 * 4 + 0) * 72 + d] = f2bf(sv.x);
            Ss[(jb + g4 * 4 + 1) * 72 + d] = f2bf(sv.y);
            Ss[(jb + g4 * 4 + 2) * 72 + d] = f2bf(sv.z);
            Ss[(jb + g4 * 4 + 3) * 72 + d] = f2bf(sv.w);
        }
    }
    if (t < 64) Ss[64 * 72 + t] = f2bf(zp[t]);  // z row
    __syncthreads();

    // ---- P = Q K^T (rows wm..wm+31) and O = Q . S_ext ----
    f32x4 Pacc[2][8], Oacc[2][5];
    #pragma unroll
    for (int i = 0; i < 2; i++) {
        #pragma unroll
        for (int n = 0; n < 8; n++) Pacc[i][n] = (f32x4){0.f, 0.f, 0.f, 0.f};
        #pragma unroll
        for (int j = 0; j < 5; j++) Oacc[i][j] = (f32x4){0.f, 0.f, 0.f, 0.f};
    }
    bf16x8 aq[2][2];
    #pragma unroll
    for (int i = 0; i < 2; i++)
        #pragma unroll
        for (int ks = 0; ks < 2; ks++)
            aq[i][ks] = *(const bf16x8*)&Qs[(wm + i * 16 + l16) * 72 + ks * 32 + quad * 8];
    #pragma unroll
    for (int n = 0; n < 8; n++)
        #pragma unroll
        for (int ks = 0; ks < 2; ks++) {
            bf16x8 bk = *(const bf16x8*)&Ks[(n * 16 + l16) * 72 + ks * 32 + quad * 8];
            #pragma unroll
            for (int i = 0; i < 2; i++)
                Pacc[i][n] = __builtin_amdgcn_mfma_f32_16x16x32_bf16(aq[i][ks], bk, Pacc[i][n], 0, 0, 0);
        }
    #pragma unroll
    for (int j = 0; j < 5; j++)
        #pragma unroll
        for (int ks = 0; ks < 2; ks++) {
            bf16x8 bs = *(const bf16x8*)&Ss[(j * 16 + l16) * 72 + ks * 32 + quad * 8];
            #pragma unroll
            for (int i = 0; i < 2; i++)
                Oacc[i][j] = __builtin_amdgcn_mfma_f32_16x16x32_bf16(aq[i][ks], bs, Oacc[i][j], 0, 0, 0);
        }
    __syncthreads();   // Q,K,S reads done — safe to overlay P

    // ---- mask + write P (bf16) ----
    #pragma unroll
    for (int i = 0; i < 2; i++)
        #pragma unroll
        for (int n = 0; n < 8; n++)
            #pragma unroll
            for (int r = 0; r < 4; r++) {
                int trow = wm + i * 16 + quad * 4 + r;
                int scol = n * 16 + l16;
                Ps[trow * 136 + scol] = (scol <= trow) ? f2bf(Pacc[i][n][r]) : 0;
            }
    __syncthreads();

    // ---- O += P . V_ext ----
    #pragma unroll
    for (int ks = 0; ks < 4; ks++) {
        bf16x8 ap[2];
        #pragma unroll
        for (int i = 0; i < 2; i++)
            ap[i] = *(const bf16x8*)&Ps[(wm + i * 16 + l16) * 136 + ks * 32 + quad * 8];
        #pragma unroll
        for (int j = 0; j < 5; j++) {
            bf16x8 bv = *(const bf16x8*)&VT[(j * 16 + l16) * 136 + ks * 32 + quad * 8];
            #pragma unroll
            for (int i = 0; i < 2; i++)
                Oacc[i][j] = __builtin_amdgcn_mfma_f32_16x16x32_bf16(ap[i], bv, Oacc[i][j], 0, 0, 0);
        }
    }
    __syncthreads();   // P reads done — safe to overlay Cout

    // ---- divide by den (col 64) and write Cout ----
    #pragma unroll
    for (int i = 0; i < 2; i++) {
        #pragma unroll
        for (int r = 0; r < 4; r++) {
            float den = __shfl(Oacc[i][4][r], lane & 48) + 1e-6f;
            float inv = 1.f / den;
            #pragma unroll
            for (int j = 0; j < 4; j++)
                Cout[(wm + i * 16 + quad * 4 + r) * 136 + j * 16 + l16] = f2bf(Oacc[i][j][r] * inv);
        }
    }
    __syncthreads();
    unsigned short* abase = attnb + rowbase * D_ + h * 64;
    #pragma unroll
    for (int p = 0; p < 4; p++) {
        int idx = p * 256 + t;
        int row = idx >> 3, cg = (idx & 7) * 8;
        *(us8*)&abase[(size_t)row * D_ + cg] = *(const us8*)&Cout[row * 136 + cg];
    }
}

extern "C" void kernel_launch(void* const* d_in, const int* in_sizes, int n_in,
                              void* d_out, int out_size, void* d_ws, size_t ws_size,
                              hipStream_t stream)
{
    char* w = (char*)d_ws;
    auto alloc = [&](size_t bytes) { void* p = (void*)w; w += (bytes + 255) & ~(size_t)255; return p; };
    int*            flagp   = (int*)alloc(256);
    unsigned short* x_c     = (unsigned short*)alloc((size_t)BL * D_ * 2);   // reused as attnb
    unsigned short* attnb   = x_c;
    unsigned short* xn      = (unsigned short*)alloc((size_t)BL * D_ * 2);
    unsigned short* WqkvT   = (unsigned short*)alloc((size_t)2304 * 768 * 2);
    unsigned short* WdT     = (unsigned short*)alloc((size_t)256 * 768 * 2);
    unsigned short* WsuT    = (unsigned short*)alloc((size_t)1536 * 128 * 2);
    unsigned short* WcuT    = (unsigned short*)alloc((size_t)1536 * 128 * 2);
    unsigned short* WprojT  = (unsigned short*)alloc((size_t)768 * 768 * 2);
    unsigned short* bqkv_c  = (unsigned short*)alloc((size_t)2304 * 2);
    unsigned short* bproj_c = (unsigned short*)alloc((size_t)768 * 2);
    unsigned short* gamma_c = (unsigned short*)alloc((size_t)768 * 2);
    unsigned short* beta_c  = (unsigned short*)alloc((size_t)768 * 2);
    unsigned short* temp_c  = (unsigned short*)alloc(256);
    unsigned short* tdown   = (unsigned short*)alloc((size_t)BL * 256 * 2);
    float*          Zsum    = (float*)alloc((size_t)BH * NC * 64 * 4);
    unsigned short* qkvt    = (unsigned short*)alloc((size_t)BL * 2304 * 2);
    float*          Msum    = (float*)alloc((size_t)BH * NC * 4096 * 4);

    dim3 blk(256);
    // 0. detect + canonicalize
    detect_kernel<<<1, blk, 0, stream>>>((const unsigned short*)d_in[0], flagp);
    convert_mega_kernel<<<12307, blk, 0, stream>>>(
        d_in[0], x_c, d_in[2], bqkv_c, d_in[9], bproj_c,
        d_in[10], gamma_c, d_in[11], beta_c, d_in[7], temp_c, flagp);
    transpose_mega_kernel<<<2880, blk, 0, stream>>>(
        d_in[1], WqkvT, d_in[3], WdT, d_in[4], WsuT,
        d_in[5], d_in[6], WcuT, d_in[8], WprojT, flagp);
    // 1. LayerNorm
    ln_kernel<<<BL, blk, 0, stream>>>(x_c, gamma_c, beta_c, xn);
    // 2. merged down-projections (silu)
    mfma_gemm_kernel<1><<<dim3(2, 32), blk, 0, stream>>>(x_c, 768, WdT, nullptr, nullptr, tdown, flagp, 256, 768);
    // 3. fused up-projections + gate -> d_out gate region
    gate_mfma_kernel<<<dim3(12, 64), blk, 0, stream>>>(tdown, WsuT, WcuT, temp_c, d_out, flagp);
    // 4. qkv GEMM with fused elu/gate epilogue
    mfma_gemm_kernel<2><<<dim3(18, 32), blk, 0, stream>>>(xn, 768, WqkvT, bqkv_c, d_out, qkvt, flagp, 2304, 768);
    // 5. chunked causal linear attention — all-MFMA
    chunk_sum_mfma_kernel<<<BH * NC, blk, 0, stream>>>(qkvt, Msum, Zsum);
    prefix_kernel<<<BH * 4, blk, 0, stream>>>(Msum, Zsum);
    chunk_scan_mfma_kernel<<<BH * NC, blk, 0, stream>>>(qkvt, Msum, Zsum, attnb);
    // 6. output projection (flagged store)
    mfma_gemm_kernel<3><<<dim3(6, 32), blk, 0, stream>>>(attnb, 768, WprojT, bproj_c, nullptr, d_out, flagp, 768, 768);
}

// Round 7
// 245.933 us; speedup vs baseline: 3.8346x; 1.0418x over previous
//
#include <hip/hip_runtime.h>

#define B_    2
#define L_    2048
#define D_    768
#define H_    12
#define BL    4096      // B_*L_
#define BH    24        // B_*H_
#define CHUNK 128
#define NC    16        // L_/CHUNK
#define GOFF  3145728   // element offset of gate output within d_out
#define PI_F  3.14159265358979f

typedef __bf16 bf16x8 __attribute__((ext_vector_type(8)));
typedef float  f32x4  __attribute__((ext_vector_type(4)));
typedef unsigned short us8 __attribute__((ext_vector_type(8)));

__device__ __forceinline__ float bf2f(unsigned short u) {
    return __uint_as_float(((unsigned int)u) << 16);
}
__device__ __forceinline__ unsigned short f2bf(float f) {
    unsigned int u = __float_as_uint(f);
    unsigned int r = (u + 0x7fffu + ((u >> 16) & 1u)) >> 16;
    return (unsigned short)r;
}
__device__ __forceinline__ float softplusf(float x) {
    return x > 20.f ? x : log1pf(expf(x));
}
// async global->LDS, 16B per lane; LDS dest = wave-uniform base + lane*16
__device__ __forceinline__ void dma16(const unsigned short* g, unsigned short* l) {
    __builtin_amdgcn_global_load_lds(
        (const __attribute__((address_space(1))) unsigned int*)g,
        (__attribute__((address_space(3))) unsigned int*)l, 16, 0, 0);
}

// ---------------- dtype detector ----------------
__global__ __launch_bounds__(256) void detect_kernel(const unsigned short* __restrict__ x,
                                                     int* __restrict__ flag)
{
    __shared__ int cnt;
    if (threadIdx.x == 0) cnt = 0;
    __syncthreads();
    int c = 0;
    #pragma unroll
    for (int i = 0; i < 16; i++) {
        unsigned short u = x[threadIdx.x * 16 + i];
        int e = (u >> 7) & 0xff;
        if (e < 100 || e > 140) c++;
    }
    atomicAdd(&cnt, c);
    __syncthreads();
    if (threadIdx.x == 0) flag[0] = (cnt > 512) ? 1 : 0;   // 1 = inputs are fp32
}

// ---------------- small-vector convert: biases/gamma/beta/temp -> bf16 ------------
__global__ __launch_bounds__(256) void convert_small_kernel(
    const void* __restrict__ s1, unsigned short* __restrict__ d1,   // bqkv 2304
    const void* __restrict__ s2, unsigned short* __restrict__ d2,   // bproj 768
    const void* __restrict__ s3, unsigned short* __restrict__ d3,   // gamma 768
    const void* __restrict__ s4, unsigned short* __restrict__ d4,   // beta 768
    const void* __restrict__ s5, unsigned short* __restrict__ d5,   // temp 1
    const int* __restrict__ flag)
{
    int id = blockIdx.x, t = threadIdx.x;
    int fl = flag[0];
    const void* src; unsigned short* dst; int n, base;
    if (id < 9)       { src = s1; dst = d1; n = 2304; base = id * 256; }
    else if (id < 12) { src = s2; dst = d2; n = 768;  base = (id - 9) * 256; }
    else if (id < 15) { src = s3; dst = d3; n = 768;  base = (id - 12) * 256; }
    else if (id < 18) { src = s4; dst = d4; n = 768;  base = (id - 15) * 256; }
    else              { src = s5; dst = d5; n = 1;    base = 0; }
    int i = base + t;
    if (i < n) dst[i] = fl ? f2bf(((const float*)src)[i]) : ((const unsigned short*)src)[i];
}

// ---------------- mega transpose: all 6 weights (K x N) -> (N x K) bf16 -----------
__global__ __launch_bounds__(256) void transpose_mega_kernel(
    const void* __restrict__ s0, unsigned short* __restrict__ dq,   // Wqkv 768x2304
    const void* __restrict__ s1, unsigned short* __restrict__ dd,   // Wsd 768x128 -> WdT[0]
    const void* __restrict__ s2, unsigned short* __restrict__ dsu,  // Wsu 128x1536
    const void* __restrict__ s3,                                    // Wcd 768x128 -> WdT[128*768]
    const void* __restrict__ s4, unsigned short* __restrict__ dcu,  // Wcu 128x1536
    const void* __restrict__ s5, unsigned short* __restrict__ dp,   // Wproj 768x768
    const int* __restrict__ flag)
{
    __shared__ unsigned short tile[32][33];
    int id = blockIdx.x;
    const void* src; unsigned short* dst; int K, N, tid;
    if (id < 1728)      { src = s0; dst = dq;  K = 768; N = 2304; tid = id; }
    else if (id < 1824) { src = s1; dst = dd;  K = 768; N = 128;  tid = id - 1728; }
    else if (id < 2016) { src = s2; dst = dsu; K = 128; N = 1536; tid = id - 1824; }
    else if (id < 2112) { src = s3; dst = dd + (size_t)128 * 768; K = 768; N = 128; tid = id - 2016; }
    else if (id < 2304) { src = s4; dst = dcu; K = 128; N = 1536; tid = id - 2112; }
    else                { src = s5; dst = dp;  K = 768; N = 768;  tid = id - 2304; }
    int tn = N / 32;
    int by = (tid / tn) * 32, bx = (tid % tn) * 32;
    int tx = threadIdx.x & 31, tyb = threadIdx.x >> 5;
    int fl = flag[0];
    #pragma unroll
    for (int i = 0; i < 4; i++) {
        int k = by + tyb * 4 + i, n = bx + tx;
        size_t off = (size_t)k * N + n;
        tile[tyb * 4 + i][tx] = fl ? f2bf(((const float*)src)[off]) : ((const unsigned short*)src)[off];
    }
    __syncthreads();
    #pragma unroll
    for (int i = 0; i < 4; i++) {
        int n = bx + tyb * 4 + i, k = by + tx;
        dst[(size_t)n * K + k] = tile[tx][tyb * 4 + i];
    }
}

// ---------------- Fused convert + LayerNorm: x -> x_c (bf16), xn (bf16) -----------
__global__ __launch_bounds__(256) void conv_ln_kernel(
    const void* __restrict__ xin,
    const unsigned short* __restrict__ gamma,
    const unsigned short* __restrict__ beta,
    unsigned short* __restrict__ x_c,
    unsigned short* __restrict__ xn,
    const int* __restrict__ flag)
{
    int row = blockIdx.x, t = threadIdx.x;
    int fl = flag[0];
    float v[3];
    #pragma unroll
    for (int j = 0; j < 3; j++) {
        int c = t + j * 256;
        v[j] = fl ? ((const float*)xin)[(size_t)row * D_ + c]
                  : bf2f(((const unsigned short*)xin)[(size_t)row * D_ + c]);
    }
    __shared__ float red[8];
    float s = v[0] + v[1] + v[2];
    #pragma unroll
    for (int m = 32; m >= 1; m >>= 1) s += __shfl_xor(s, m, 64);
    int wid = t >> 6;
    if ((t & 63) == 0) red[wid] = s;
    __syncthreads();
    float mean = (red[0] + red[1] + red[2] + red[3]) * (1.f / 768.f);
    float s2 = 0.f;
    #pragma unroll
    for (int j = 0; j < 3; j++) { float d = v[j] - mean; s2 += d * d; }
    #pragma unroll
    for (int m = 32; m >= 1; m >>= 1) s2 += __shfl_xor(s2, m, 64);
    if ((t & 63) == 0) red[4 + wid] = s2;
    __syncthreads();
    float var = (red[4] + red[5] + red[6] + red[7]) * (1.f / 768.f);
    float rs = rsqrtf(var + 1e-5f);
    #pragma unroll
    for (int j = 0; j < 3; j++) {
        int c = t + j * 256;
        x_c[(size_t)row * D_ + c] = f2bf(v[j]);
        float o = (v[j] - mean) * rs * bf2f(gamma[c]) + bf2f(beta[c]);
        xn[(size_t)row * D_ + c] = f2bf(o);
    }
}

// ---------------- MFMA GEMM v3: global_load_lds staging + XOR-swizzled LDS --------
// A: 4096 x K (lda). BT: N x K. 128x128 tile, 4 waves, 4x4 mfma_16x16x32 per wave.
// LDS tiles [128][64] bf16 unpadded; logical (row, colg) stored at colg ^ (row&7).
// EPI: 0 bias, 1 silu, 2 qkv transform (gateb bf16), 3 flagged final store
template<int EPI>
__global__ __launch_bounds__(256) void mfma_gemm_kernel(
    const unsigned short* __restrict__ A, int lda,
    const unsigned short* __restrict__ BT,
    const unsigned short* __restrict__ bias,
    const unsigned short* __restrict__ gateb,   // EPI==2: bf16 gate (BL x 768)
    void* __restrict__ outp,
    const int* __restrict__ flag,
    int N, int K)
{
    __shared__ unsigned short sbuf[17408];      // 34816 B
    unsigned short* As = sbuf;                  // [128][64]
    unsigned short* Bs = sbuf + 8192;           // [128][64]
    unsigned short* Cs = sbuf;                  // [128][136] overlay

    int f = blockIdx.y * gridDim.x + blockIdx.x;
    int rps = gridDim.y >> 3;
    int strip = f & 7, within = f >> 3;
    int by = strip * rps + (within % rps);
    int bx = within / rps;
    int m0 = by * 128, n0 = bx * 128;

    int t = threadIdx.x;
    int lane = t & 63, wave = t >> 6, quad = lane >> 4, l16 = lane & 15;
    int wm = (wave & 1) * 64, wn = (wave >> 1) * 64;
    int xr = l16 & 7;

    // staging: wave handles rows [wave*32, wave*32+32); lane covers (row8=lane>>3,
    // physical colg'=lane&7) which holds logical colg = (lane&7)^(lane>>3)
    int sr8 = lane >> 3;
    int scg = (lane & 7) ^ sr8;
    const unsigned short* ApL = A  + (size_t)(m0 + wave * 32 + sr8) * lda + scg * 8;
    const unsigned short* BpL = BT + (size_t)(n0 + wave * 32 + sr8) * K   + scg * 8;
    unsigned short* AsW = As + wave * 32 * 64;
    unsigned short* BsW = Bs + wave * 32 * 64;

    f32x4 acc[4][4];
    #pragma unroll
    for (int i = 0; i < 4; i++)
        #pragma unroll
        for (int j = 0; j < 4; j++) acc[i][j] = (f32x4){0.f, 0.f, 0.f, 0.f};

    for (int k0 = 0; k0 < K; k0 += 64) {
        __syncthreads();                         // prior LDS reads done
        #pragma unroll
        for (int c = 0; c < 4; c++) {
            dma16(ApL + (size_t)(c * 8) * lda + k0, AsW + c * 512);
            dma16(BpL + (size_t)(c * 8) * K   + k0, BsW + c * 512);
        }
        __syncthreads();                         // drains vmcnt(0): LDS ready
        #pragma unroll
        for (int ks = 0; ks < 2; ks++) {
            bf16x8 af[4], bfr[4];
            #pragma unroll
            for (int i = 0; i < 4; i++)
                af[i] = *(const bf16x8*)&As[(wm + i * 16 + l16) * 64 + (((ks * 4 + quad) ^ xr) * 8)];
            #pragma unroll
            for (int j = 0; j < 4; j++)
                bfr[j] = *(const bf16x8*)&Bs[(wn + j * 16 + l16) * 64 + (((ks * 4 + quad) ^ xr) * 8)];
            #pragma unroll
            for (int i = 0; i < 4; i++)
                #pragma unroll
                for (int j = 0; j < 4; j++)
                    acc[i][j] = __builtin_amdgcn_mfma_f32_16x16x32_bf16(af[i], bfr[j], acc[i][j], 0, 0, 0);
        }
    }

    int fl = (EPI == 3) ? flag[0] : 0;
    __syncthreads();                             // LDS reads done; Cs overlays As/Bs
    #pragma unroll
    for (int j = 0; j < 4; j++) {
        int col = n0 + wn + j * 16 + l16;
        float bv = bias ? bf2f(bias[col]) : 0.f;
        #pragma unroll
        for (int i = 0; i < 4; i++) {
            #pragma unroll
            for (int r = 0; r < 4; r++) {
                int row = m0 + wm + i * 16 + quad * 4 + r;
                float v = acc[i][j][r] + bv;
                if (EPI == 1) v = v / (1.f + expf(-v));
                if (EPI == 2) {
                    if (col < D_) {
                        v = v > 0.f ? v + 1.f : expf(v);
                    } else if (col < 2 * D_) {
                        float gg = bf2f(gateb[(size_t)row * D_ + (col - D_)]);
                        v *= (1.f + gg);
                        v = v > 0.f ? v + 1.f : expf(v);
                    }
                }
                if (EPI == 3 && fl) {
                    ((float*)outp)[(size_t)row * N + col] = v;
                } else {
                    Cs[(wm + i * 16 + quad * 4 + r) * 136 + wn + j * 16 + l16] = f2bf(v);
                }
            }
        }
    }
    if (!(EPI == 3 && fl)) {
        __syncthreads();
        #pragma unroll
        for (int p = 0; p < 8; p++) {
            int idx = p * 256 + t;
            int row = idx >> 4, cc = (idx & 15) * 8;
            *(us8*)&((unsigned short*)outp)[(size_t)(m0 + row) * N + n0 + cc] =
                *(const us8*)&Cs[row * 136 + cc];
        }
    }
}

// ---------------- Fused up-projections + interference gate -----------------------
__global__ __launch_bounds__(256) void gate_mfma_kernel(
    const unsigned short* __restrict__ tdown,
    const unsigned short* __restrict__ WsuT,
    const unsigned short* __restrict__ WcuT,
    const unsigned short* __restrict__ tempc,
    void* __restrict__ dout,
    unsigned short* __restrict__ gateb,
    const int* __restrict__ flag)
{
    __shared__ unsigned short gbuf[4 * 64 * 68];
    int f = blockIdx.y * gridDim.x + blockIdx.x;
    int rps = gridDim.y >> 3;
    int strip = f & 7, within = f >> 3;
    int by = strip * rps + (within % rps);
    int bx = within / rps;
    int m0 = by * 64, c0 = bx * 64;

    int t = threadIdx.x;
    int lane = t & 63, wave = t >> 6, quad = lane >> 4, l16 = lane & 15;
    int tr = t >> 2, tc = (t & 3) * 8;
    f32x4 acc[4][4];
    #pragma unroll
    for (int i = 0; i < 4; i++)
        #pragma unroll
        for (int j = 0; j < 4; j++) acc[i][j] = (f32x4){0.f, 0.f, 0.f, 0.f};

    int Atile = wave >> 1, Btile = 2 + wave;
    for (int k0 = 0; k0 < 128; k0 += 32) {
        us8 v0 = *(const us8*)&tdown[(size_t)(m0 + tr) * 256 + k0 + tc];
        us8 v1 = *(const us8*)&tdown[(size_t)(m0 + tr) * 256 + 128 + k0 + tc];
        us8 v2 = *(const us8*)&WsuT[(size_t)(c0 + tr) * 128 + k0 + tc];
        us8 v3 = *(const us8*)&WsuT[(size_t)(768 + c0 + tr) * 128 + k0 + tc];
        us8 v4 = *(const us8*)&WcuT[(size_t)(c0 + tr) * 128 + k0 + tc];
        us8 v5 = *(const us8*)&WcuT[(size_t)(768 + c0 + tr) * 128 + k0 + tc];
        __syncthreads();
        *(us8*)&gbuf[0 * 2560 + tr * 40 + tc] = v0;
        *(us8*)&gbuf[1 * 2560 + tr * 40 + tc] = v1;
        *(us8*)&gbuf[2 * 2560 + tr * 40 + tc] = v2;
        *(us8*)&gbuf[3 * 2560 + tr * 40 + tc] = v3;
        *(us8*)&gbuf[4 * 2560 + tr * 40 + tc] = v4;
        *(us8*)&gbuf[5 * 2560 + tr * 40 + tc] = v5;
        __syncthreads();
        bf16x8 af[4], bfr[4];
        #pragma unroll
        for (int i = 0; i < 4; i++)
            af[i] = *(const bf16x8*)&gbuf[Atile * 2560 + (i * 16 + l16) * 40 + quad * 8];
        #pragma unroll
        for (int j = 0; j < 4; j++)
            bfr[j] = *(const bf16x8*)&gbuf[Btile * 2560 + (j * 16 + l16) * 40 + quad * 8];
        #pragma unroll
        for (int i = 0; i < 4; i++)
            #pragma unroll
            for (int j = 0; j < 4; j++)
                acc[i][j] = __builtin_amdgcn_mfma_f32_16x16x32_bf16(af[i], bfr[j], acc[i][j], 0, 0, 0);
    }
    __syncthreads();
    #pragma unroll
    for (int i = 0; i < 4; i++)
        #pragma unroll
        for (int j = 0; j < 4; j++)
            #pragma unroll
            for (int r = 0; r < 4; r++)
                gbuf[wave * 4352 + (i * 16 + quad * 4 + r) * 68 + j * 16 + l16] = f2bf(acc[i][j][r]);
    __syncthreads();
    float tempv = bf2f(tempc[0]);
    int fl = flag[0];
    #pragma unroll
    for (int p = 0; p < 16; p++) {
        int idx = p * 256 + t;
        int row = idx >> 6, col = idx & 63;
        float sa = softplusf(bf2f(gbuf[0 * 4352 + row * 68 + col]));
        float sp = tanhf(bf2f(gbuf[1 * 4352 + row * 68 + col])) * PI_F;
        float ca = softplusf(bf2f(gbuf[2 * 4352 + row * 68 + col]));
        float cp = tanhf(bf2f(gbuf[3 * 4352 + row * 68 + col])) * PI_F;
        float inter = sa * ca * cosf(sp - cp) * tempv;
        float g = 1.f / (1.f + expf(-inter));
        size_t off = (size_t)GOFF + (size_t)(m0 + row) * D_ + c0 + col;
        unsigned short gb = f2bf(g);
        if (fl) ((float*)dout)[off] = g;
        else    ((unsigned short*)dout)[off] = gb;
        gateb[(size_t)(m0 + row) * D_ + c0 + col] = gb;
    }
}

// ---------------- Pass A (MFMA): S_c = K^T . V_ext per (bh,chunk) -----------------
__global__ __launch_bounds__(256) void chunk_sum_mfma_kernel(
    const unsigned short* __restrict__ qkvt,
    float* __restrict__ Msum, float* __restrict__ Zsum)
{
    __shared__ __align__(16) unsigned short KT[64 * 136];
    __shared__ __align__(16) unsigned short VT[80 * 136];
    int blk = blockIdx.x;
    int bh = blk / NC, cc = blk - bh * NC;
    int b = bh / H_, h = bh - b * H_;
    int t = threadIdx.x;
    int lane = t & 63, wave = t >> 6, quad = lane >> 4, l16 = lane & 15;
    int lr = t >> 1, lc = (t & 1) * 32;
    size_t rowbase = (size_t)(b * L_ + cc * CHUNK);
    const unsigned short* kg = qkvt + rowbase * 2304 + D_ + h * 64;
    const unsigned short* vg = qkvt + rowbase * 2304 + 2 * D_ + h * 64;
    #pragma unroll
    for (int c = 0; c < 4; c++) {
        us8 kv = *(const us8*)&kg[(size_t)lr * 2304 + lc + c * 8];
        us8 vv = *(const us8*)&vg[(size_t)lr * 2304 + lc + c * 8];
        #pragma unroll
        for (int ii = 0; ii < 8; ii++) {
            KT[(lc + c * 8 + ii) * 136 + lr] = kv[ii];
            VT[(lc + c * 8 + ii) * 136 + lr] = vv[ii];
        }
    }
    if (t < 128) VT[64 * 136 + t] = 0x3F80;   // ones row (bf16 1.0)
    __syncthreads();

    f32x4 acc[5];
    #pragma unroll
    for (int j = 0; j < 5; j++) acc[j] = (f32x4){0.f, 0.f, 0.f, 0.f};
    #pragma unroll
    for (int ks = 0; ks < 4; ks++) {
        bf16x8 a = *(const bf16x8*)&KT[(wave * 16 + l16) * 136 + ks * 32 + quad * 8];
        #pragma unroll
        for (int j = 0; j < 5; j++) {
            bf16x8 bv = *(const bf16x8*)&VT[(j * 16 + l16) * 136 + ks * 32 + quad * 8];
            acc[j] = __builtin_amdgcn_mfma_f32_16x16x32_bf16(a, bv, acc[j], 0, 0, 0);
        }
    }
    float* mo = Msum + (size_t)blk * 4096;
    #pragma unroll
    for (int j = 0; j < 4; j++)
        #pragma unroll
        for (int r = 0; r < 4; r++)
            mo[(wave * 16 + quad * 4 + r) * 64 + j * 16 + l16] = acc[j][r];
    if (l16 == 0) {
        #pragma unroll
        for (int r = 0; r < 4; r++)
            Zsum[(size_t)blk * 64 + wave * 16 + quad * 4 + r] = acc[4][r];
    }
}

// ---------------- Pass B: in-register exclusive prefix (grid = BH*4) --------------
__global__ __launch_bounds__(256) void prefix_kernel(
    float* __restrict__ Msum, float* __restrict__ Zsum)
{
    int blk = blockIdx.x;
    int bh = blk >> 2, qd = blk & 3;
    int t = threadIdx.x;
    size_t base = (size_t)bh * NC * 4096 + qd * 1024 + t * 4;
    float4 v[NC];
    #pragma unroll
    for (int c = 0; c < NC; c++) v[c] = *(const float4*)&Msum[base + (size_t)c * 4096];
    float4 run = make_float4(0.f, 0.f, 0.f, 0.f);
    #pragma unroll
    for (int c = 0; c < NC; c++) {
        float4 tmp = v[c];
        *(float4*)&Msum[base + (size_t)c * 4096] = run;
        run.x += tmp.x; run.y += tmp.y; run.z += tmp.z; run.w += tmp.w;
    }
    if (qd == 0 && t < 64) {
        float rz = 0.f;
        for (int c = 0; c < NC; c++) {
            float* pz = &Zsum[((size_t)bh * NC + c) * 64 + t];
            float vv = *pz; *pz = rz; rz += vv;
        }
    }
}

// ---------------- Pass C (MFMA): O = Q.S_prefix + tril(QK^T).V --------------------
__global__ __launch_bounds__(256) void chunk_scan_mfma_kernel(
    const unsigned short* __restrict__ qkvt,
    const float* __restrict__ Msum, const float* __restrict__ Zsum,
    unsigned short* __restrict__ attnb)
{
    __shared__ __align__(16) unsigned short sbuf[35072];
    unsigned short* Qs = sbuf;                  // 128*72
    unsigned short* Ks = sbuf + 9216;           // 128*72
    unsigned short* Ps = sbuf;                  // 128*136 (overlay Q+K)
    unsigned short* VT = sbuf + 18432;          // 80*136
    unsigned short* Ss = sbuf + 29312;          // 80*72
    unsigned short* Cout = sbuf;                // 128*136 (overlay P)

    int blk = blockIdx.x;
    int bh = blk / NC, cc = blk - bh * NC;
    int b = bh / H_, h = bh - b * H_;
    int t = threadIdx.x;
    int lane = t & 63, wave = t >> 6, quad = lane >> 4, l16 = lane & 15;
    int wm = wave * 32;
    int lr = t >> 1, lc = (t & 1) * 32;
    size_t rowbase = (size_t)(b * L_ + cc * CHUNK);
    const unsigned short* qg = qkvt + rowbase * 2304 + h * 64;
    const unsigned short* kg = qkvt + rowbase * 2304 + D_ + h * 64;
    const unsigned short* vg = qkvt + rowbase * 2304 + 2 * D_ + h * 64;
    const float* mp = Msum + (size_t)blk * 4096;
    const float* zp = Zsum + (size_t)blk * 64;

    #pragma unroll
    for (int c = 0; c < 4; c++) {
        us8 qv = *(const us8*)&qg[(size_t)lr * 2304 + lc + c * 8];
        us8 kv = *(const us8*)&kg[(size_t)lr * 2304 + lc + c * 8];
        us8 vv = *(const us8*)&vg[(size_t)lr * 2304 + lc + c * 8];
        *(us8*)&Qs[lr * 72 + lc + c * 8] = qv;
        *(us8*)&Ks[lr * 72 + lc + c * 8] = kv;
        #pragma unroll
        for (int ii = 0; ii < 8; ii++)
            VT[(lc + c * 8 + ii) * 136 + lr] = vv[ii];
    }
    if (t < 128) VT[64 * 136 + t] = 0x3F80;     // ones row
    {
        int d = t & 63, jb = (t >> 6) * 16;
        #pragma unroll
        for (int g4 = 0; g4 < 4; g4++) {
            float4 sv = *(const float4*)&mp[d * 64 + jb + g4 * 4];
            Ss[(jb + g4 * 4 + 0) * 72 + d] = f2bf(sv.x);
            Ss[(jb + g4 * 4 + 1) * 72 + d] = f2bf(sv.y);
            Ss[(jb + g4 * 4 + 2) * 72 + d] = f2bf(sv.z);
            Ss[(jb + g4 * 4 + 3) * 72 + d] = f2bf(sv.w);
        }
    }
    if (t < 64) Ss[64 * 72 + t] = f2bf(zp[t]);  // z row
    __syncthreads();

    f32x4 Pacc[2][8], Oacc[2][5];
    #pragma unroll
    for (int i = 0; i < 2; i++) {
        #pragma unroll
        for (int n = 0; n < 8; n++) Pacc[i][n] = (f32x4){0.f, 0.f, 0.f, 0.f};
        #pragma unroll
        for (int j = 0; j < 5; j++) Oacc[i][j] = (f32x4){0.f, 0.f, 0.f, 0.f};
    }
    bf16x8 aq[2][2];
    #pragma unroll
    for (int i = 0; i < 2; i++)
        #pragma unroll
        for (int ks = 0; ks < 2; ks++)
            aq[i][ks] = *(const bf16x8*)&Qs[(wm + i * 16 + l16) * 72 + ks * 32 + quad * 8];
    #pragma unroll
    for (int n = 0; n < 8; n++)
        #pragma unroll
        for (int ks = 0; ks < 2; ks++) {
            bf16x8 bk = *(const bf16x8*)&Ks[(n * 16 + l16) * 72 + ks * 32 + quad * 8];
            #pragma unroll
            for (int i = 0; i < 2; i++)
                Pacc[i][n] = __builtin_amdgcn_mfma_f32_16x16x32_bf16(aq[i][ks], bk, Pacc[i][n], 0, 0, 0);
        }
    #pragma unroll
    for (int j = 0; j < 5; j++)
        #pragma unroll
        for (int ks = 0; ks < 2; ks++) {
            bf16x8 bs = *(const bf16x8*)&Ss[(j * 16 + l16) * 72 + ks * 32 + quad * 8];
            #pragma unroll
            for (int i = 0; i < 2; i++)
                Oacc[i][j] = __builtin_amdgcn_mfma_f32_16x16x32_bf16(aq[i][ks], bs, Oacc[i][j], 0, 0, 0);
        }
    __syncthreads();

    #pragma unroll
    for (int i = 0; i < 2; i++)
        #pragma unroll
        for (int n = 0; n < 8; n++)
            #pragma unroll
            for (int r = 0; r < 4; r++) {
                int trow = wm + i * 16 + quad * 4 + r;
                int scol = n * 16 + l16;
                Ps[trow * 136 + scol] = (scol <= trow) ? f2bf(Pacc[i][n][r]) : 0;
            }
    __syncthreads();

    #pragma unroll
    for (int ks = 0; ks < 4; ks++) {
        bf16x8 ap[2];
        #pragma unroll
        for (int i = 0; i < 2; i++)
            ap[i] = *(const bf16x8*)&Ps[(wm + i * 16 + l16) * 136 + ks * 32 + quad * 8];
        #pragma unroll
        for (int j = 0; j < 5; j++) {
            bf16x8 bv = *(const bf16x8*)&VT[(j * 16 + l16) * 136 + ks * 32 + quad * 8];
            #pragma unroll
            for (int i = 0; i < 2; i++)
                Oacc[i][j] = __builtin_amdgcn_mfma_f32_16x16x32_bf16(ap[i], bv, Oacc[i][j], 0, 0, 0);
        }
    }
    __syncthreads();

    #pragma unroll
    for (int i = 0; i < 2; i++) {
        #pragma unroll
        for (int r = 0; r < 4; r++) {
            float den = __shfl(Oacc[i][4][r], lane & 48) + 1e-6f;
            float inv = 1.f / den;
            #pragma unroll
            for (int j = 0; j < 4; j++)
                Cout[(wm + i * 16 + quad * 4 + r) * 136 + j * 16 + l16] = f2bf(Oacc[i][j][r] * inv);
        }
    }
    __syncthreads();
    unsigned short* abase = attnb + rowbase * D_ + h * 64;
    #pragma unroll
    for (int p = 0; p < 4; p++) {
        int idx = p * 256 + t;
        int row = idx >> 3, cg = (idx & 7) * 8;
        *(us8*)&abase[(size_t)row * D_ + cg] = *(const us8*)&Cout[row * 136 + cg];
    }
}

extern "C" void kernel_launch(void* const* d_in, const int* in_sizes, int n_in,
                              void* d_out, int out_size, void* d_ws, size_t ws_size,
                              hipStream_t stream)
{
    char* w = (char*)d_ws;
    auto alloc = [&](size_t bytes) { void* p = (void*)w; w += (bytes + 255) & ~(size_t)255; return p; };
    int*            flagp   = (int*)alloc(256);
    unsigned short* x_c     = (unsigned short*)alloc((size_t)BL * D_ * 2);   // reused as attnb
    unsigned short* attnb   = x_c;
    unsigned short* xn      = (unsigned short*)alloc((size_t)BL * D_ * 2);
    unsigned short* WqkvT   = (unsigned short*)alloc((size_t)2304 * 768 * 2);
    unsigned short* WdT     = (unsigned short*)alloc((size_t)256 * 768 * 2);
    unsigned short* WsuT    = (unsigned short*)alloc((size_t)1536 * 128 * 2);
    unsigned short* WcuT    = (unsigned short*)alloc((size_t)1536 * 128 * 2);
    unsigned short* WprojT  = (unsigned short*)alloc((size_t)768 * 768 * 2);
    unsigned short* bqkv_c  = (unsigned short*)alloc((size_t)2304 * 2);
    unsigned short* bproj_c = (unsigned short*)alloc((size_t)768 * 2);
    unsigned short* gamma_c = (unsigned short*)alloc((size_t)768 * 2);
    unsigned short* beta_c  = (unsigned short*)alloc((size_t)768 * 2);
    unsigned short* temp_c  = (unsigned short*)alloc(256);
    unsigned short* tdown   = (unsigned short*)alloc((size_t)BL * 256 * 2);
    float*          Zsum    = (float*)alloc((size_t)BH * NC * 64 * 4);
    unsigned short* qkvt    = (unsigned short*)alloc((size_t)BL * 2304 * 2);
    float*          Msum    = (float*)alloc((size_t)BH * NC * 4096 * 4);
    // gateb aliases Msum: gate written @t3, read by qkv @t4; Msum written @t5. Exact fit.
    unsigned short* gateb   = (unsigned short*)Msum;

    dim3 blk(256);
    // 0. detect + canonicalize
    detect_kernel<<<1, blk, 0, stream>>>((const unsigned short*)d_in[0], flagp);
    convert_small_kernel<<<19, blk, 0, stream>>>(
        d_in[2], bqkv_c, d_in[9], bproj_c, d_in[10], gamma_c,
        d_in[11], beta_c, d_in[7], temp_c, flagp);
    transpose_mega_kernel<<<2880, blk, 0, stream>>>(
        d_in[1], WqkvT, d_in[3], WdT, d_in[4], WsuT,
        d_in[5], d_in[6], WcuT, d_in[8], WprojT, flagp);
    // 1. fused convert + LayerNorm
    conv_ln_kernel<<<BL, blk, 0, stream>>>(d_in[0], gamma_c, beta_c, x_c, xn, flagp);
    // 2. merged down-projections (silu)
    mfma_gemm_kernel<1><<<dim3(2, 32), blk, 0, stream>>>(x_c, 768, WdT, nullptr, nullptr, tdown, flagp, 256, 768);
    // 3. fused up-projections + gate -> d_out gate region + bf16 shadow
    gate_mfma_kernel<<<dim3(12, 64), blk, 0, stream>>>(tdown, WsuT, WcuT, temp_c, d_out, gateb, flagp);
    // 4. qkv GEMM with fused elu/gate epilogue
    mfma_gemm_kernel<2><<<dim3(18, 32), blk, 0, stream>>>(xn, 768, WqkvT, bqkv_c, gateb, qkvt, flagp, 2304, 768);
    // 5. chunked causal linear attention — all-MFMA
    chunk_sum_mfma_kernel<<<BH * NC, blk, 0, stream>>>(qkvt, Msum, Zsum);
    prefix_kernel<<<BH * 4, blk, 0, stream>>>(Msum, Zsum);
    chunk_scan_mfma_kernel<<<BH * NC, blk, 0, stream>>>(qkvt, Msum, Zsum, attnb);
    // 6. output projection (flagged store)
    mfma_gemm_kernel<3><<<dim3(6, 32), blk, 0, stream>>>(attnb, 768, WprojT, bproj_c, nullptr, d_out, flagp, 768, 768);
}